// Round 9
// baseline (831.100 us; speedup 1.0000x reference)
//
#include <hip/hip_runtime.h>

#define N_  128
#define C_  64
#define T_  128
#define V_  25
#define CO_ 128
#define H_  3
#define D_  16

constexpr int COLS = 3200;
constexpr float EPSF = 1e-5f;

typedef __attribute__((ext_vector_type(8))) short short8;
typedef __attribute__((ext_vector_type(8))) unsigned short ushort8;
typedef __attribute__((ext_vector_type(4))) unsigned short us4v;
typedef __attribute__((ext_vector_type(4))) float f32x4;

// ---- workspace layout (float units) ----
constexpr size_t OFF_ATT  = 0;                          // 240,000
constexpr size_t OFF_XTHI = 240000;                     // 13,107,200 fl (26.2M ushorts)
constexpr size_t OFF_BIG  = OFF_XTHI + 13107200;        // time-shared:
//   phase A: qk bf16 [n][96][3200] (19.7M fl) ; part at +20M fl
//   phase C: x2T bf16 [n][3200][128] (26.2M fl)
constexpr size_t BIGF     = 78643200;
constexpr size_t OFF_PART = OFF_BIG + 20000000;         // 960,000 floats (4*384*625)
constexpr size_t OFF_W    = OFF_BIG + BIGF;
constexpr size_t OFF_WQHI  = OFF_W;                     // 96*64 us = 3072 fl
constexpr size_t OFF_WA3HI = OFF_WQHI + 3072;           // 128*256 us = 16384 fl
constexpr size_t OFF_WA4HI = OFF_WA3HI + 16384;         // 128*192 us = 12288 fl
constexpr size_t OFF_WA5HI = OFF_WA4HI + 12288;         // 128*1024 us = 65536 fl
constexpr size_t OFF_B3    = OFF_WA5HI + 65536;
constexpr size_t OFF_B4    = OFF_B3 + 128;
constexpr size_t OFF_B5    = OFF_B4 + 128;

__device__ __forceinline__ float lrelu(float y) { return y >= 0.f ? y : 0.1f * y; }

__device__ __forceinline__ unsigned short f2bf_rne(float f) {
    unsigned int u = __builtin_bit_cast(unsigned int, f);
    u += 0x7FFFu + ((u >> 16) & 1u);
    return (unsigned short)(u >> 16);
}
__device__ __forceinline__ float bf2f(unsigned short b) {
    unsigned int u = ((unsigned int)b) << 16;
    return __builtin_bit_cast(float, u);
}

// ---- K0: BN-fold + bf16 A-operands (single plane) ----
__global__ void k0_prep(const float* __restrict__ w_qkv,
                        const float* __restrict__ w_out, const float* __restrict__ b_out,
                        const float* __restrict__ g_out, const float* __restrict__ be_out,
                        const float* __restrict__ m_out, const float* __restrict__ v_out,
                        const float* __restrict__ w_ff,  const float* __restrict__ b_ff,
                        const float* __restrict__ g_ff,  const float* __restrict__ be_ff,
                        const float* __restrict__ m_ff,  const float* __restrict__ v_ff,
                        const float* __restrict__ w_t,   const float* __restrict__ b_t,
                        const float* __restrict__ g_t,   const float* __restrict__ be_t,
                        const float* __restrict__ m_t,   const float* __restrict__ v_t,
                        const float* __restrict__ w_ress,const float* __restrict__ b_ress,
                        const float* __restrict__ g_ress,const float* __restrict__ be_ress,
                        const float* __restrict__ m_ress,const float* __restrict__ v_ress,
                        const float* __restrict__ w_rest,const float* __restrict__ b_rest,
                        const float* __restrict__ g_rest,const float* __restrict__ be_rest,
                        const float* __restrict__ m_rest,const float* __restrict__ v_rest,
                        float* __restrict__ ws)
{
    int tid = blockIdx.x * blockDim.x + threadIdx.x;
    int np = gridDim.x * blockDim.x;

    unsigned short* wqh = (unsigned short*)(ws + OFF_WQHI);
    for (int idx = tid; idx < 96 * 64; idx += np)
        wqh[idx] = f2bf_rne(w_qkv[idx]);

    unsigned short* w3h = (unsigned short*)(ws + OFF_WA3HI);
    for (int idx = tid; idx < 128 * 256; idx += np) {
        int o = idx >> 8, k = idx & 255;
        float val;
        if (k < 192) {
            float sc = g_out[o] * rsqrtf(v_out[o] + EPSF);
            val = w_out[o * 192 + k] * sc;
        } else {
            float sc = g_ress[o] * rsqrtf(v_ress[o] + EPSF);
            val = w_ress[o * 64 + (k - 192)] * sc;
        }
        w3h[idx] = f2bf_rne(val);
    }

    unsigned short* w4h = (unsigned short*)(ws + OFF_WA4HI);
    for (int idx = tid; idx < 128 * 192; idx += np) {
        int o = idx / 192, k = idx % 192;
        float val;
        if (k < 128) {
            float sc = g_ff[o] * rsqrtf(v_ff[o] + EPSF);
            val = w_ff[o * 128 + k] * sc;
        } else {
            float sc = g_ress[o] * rsqrtf(v_ress[o] + EPSF);
            val = w_ress[o * 64 + (k - 128)] * sc;
        }
        w4h[idx] = f2bf_rne(val);
    }

    unsigned short* w5h = (unsigned short*)(ws + OFF_WA5HI);
    for (int idx = tid; idx < 128 * 1024; idx += np) {
        int o = idx >> 10, kk = idx & 1023;
        int tap = kk >> 7, i = kk & 127;
        float val;
        if (tap < 7) {
            float sc = g_t[o] * rsqrtf(v_t[o] + EPSF);
            val = w_t[((size_t)o * 128 + i) * 7 + tap] * sc;
        } else {
            float sc = g_rest[o] * rsqrtf(v_rest[o] + EPSF);
            val = w_rest[o * 128 + i] * sc;
        }
        w5h[idx] = f2bf_rne(val);
    }

    for (int o = tid; o < 128; o += np) {
        float sco = g_out[o] * rsqrtf(v_out[o] + EPSF);
        float scr = g_ress[o] * rsqrtf(v_ress[o] + EPSF);
        float scf = g_ff[o] * rsqrtf(v_ff[o] + EPSF);
        float sct = g_t[o] * rsqrtf(v_t[o] + EPSF);
        float sce = g_rest[o] * rsqrtf(v_rest[o] + EPSF);
        float bres = (b_ress[o] - m_ress[o]) * scr + be_ress[o];
        ws[OFF_B3 + o] = (b_out[o] - m_out[o]) * sco + be_out[o] + bres;
        ws[OFF_B4 + o] = (b_ff[o] - m_ff[o]) * scf + be_ff[o] + bres;
        ws[OFF_B5 + o] = (b_t[o] - m_t[o]) * sct + be_t[o]
                       + (b_rest[o] - m_rest[o]) * sce + be_rest[o];
    }
}

// ---- k_xt: x[n][c][t][v] -> xT[n][col][64] bf16 ----
__global__ __launch_bounds__(256) void k_xt(const float* __restrict__ x,
                                            unsigned short* __restrict__ xthi)
{
    __shared__ float Xs[64][26];
    int nt = blockIdx.x;
    int n = nt >> 7, t = nt & 127;
    const float* xb = x + ((size_t)n * C_ * T_ + t) * V_;
    for (int e = threadIdx.x; e < 1600; e += 256) {
        int c = e / 25, u = e % 25;
        Xs[c][u] = xb[(size_t)c * (T_ * V_) + u];
    }
    __syncthreads();
    unsigned short* dh = xthi + ((size_t)n * COLS + t * 25) * 64;
    for (int e = threadIdx.x; e < 1600; e += 256) {
        int v = e >> 6, c = e & 63;
        dh[(size_t)v * 64 + c] = f2bf_rne(Xs[c][v]);
    }
}

// ---- k1: qkv GEMM M=96,K=64 -> qk bf16 [n][96][3200] ----
__global__ __launch_bounds__(256, 2) void k1_mfma(const unsigned short* __restrict__ wqh,
                                                   const unsigned short* __restrict__ xthi,
                                                   const float* __restrict__ b_qkv,
                                                   unsigned short* __restrict__ qk)
{
    __shared__ unsigned short Ah[96][40], Bh[128][40];
    int blk = blockIdx.x;
    int n = blk / 25, ct = blk % 25;
    int c0 = ct * 128;
    int tid = threadIdx.x, lane = tid & 63, wid = tid >> 6;
    int wm = wid & 1, wn = wid >> 1;
    const unsigned short* xh = xthi + (size_t)n * COLS * 64;
    f32x4 acc[3][4];
#pragma unroll
    for (int a = 0; a < 3; ++a)
#pragma unroll
        for (int b = 0; b < 4; ++b) acc[a][b] = (f32x4)0.f;
    int rbase = lane & 15, koff = (lane >> 4) * 8;

    for (int ks = 0; ks < 2; ++ks) {
        __syncthreads();
        for (int L = tid; L < 384; L += 256) {
            int o = L >> 2, g = (L & 3) * 8;
            *(ushort8*)&Ah[o][g] = *(const ushort8*)&wqh[(size_t)o * 64 + ks * 32 + g];
        }
        for (int L = tid; L < 512; L += 256) {
            int col = L >> 2, g = (L & 3) * 8;
            size_t src = (size_t)(c0 + col) * 64 + ks * 32 + g;
            *(ushort8*)&Bh[col][g] = *(const ushort8*)&xh[src];
        }
        __syncthreads();
        short8 afh[3], bfh[4];
#pragma unroll
        for (int mb = 0; mb < 3; ++mb)
            afh[mb] = *(const short8*)&Ah[wm * 48 + mb * 16 + rbase][koff];
#pragma unroll
        for (int nb = 0; nb < 4; ++nb)
            bfh[nb] = *(const short8*)&Bh[wn * 64 + nb * 16 + rbase][koff];
#pragma unroll
        for (int mb = 0; mb < 3; ++mb)
#pragma unroll
            for (int nb = 0; nb < 4; ++nb)
                acc[mb][nb] = __builtin_amdgcn_mfma_f32_16x16x32_bf16(afh[mb], bfh[nb], acc[mb][nb], 0, 0, 0);
    }
#pragma unroll
    for (int mb = 0; mb < 3; ++mb) {
#pragma unroll
        for (int nb = 0; nb < 4; ++nb) {
            int col = c0 + wn * 64 + nb * 16 + (lane & 15);
#pragma unroll
            for (int r = 0; r < 4; ++r) {
                int o = wm * 48 + mb * 16 + (lane >> 4) * 4 + r;
                qk[((size_t)n * 96 + o) * COLS + col] = f2bf_rne(acc[mb][nb][r] + b_qkv[o]);
            }
        }
    }
}

// ---- k2: partial attention logits (T split 4-way) -> part[p][nh][u][v] ----
__global__ __launch_bounds__(256) void k2_att(const unsigned short* __restrict__ qk,
                                              float* __restrict__ part)
{
    int blk = blockIdx.x;
    int nh = blk >> 2, p = blk & 3;
    int n = nh / H_, h = nh % H_;
    __shared__ float Qs[D_][8][26];
    __shared__ float Ks[D_][8][26];
    float acc[3] = {0.f, 0.f, 0.f};
    const unsigned short* qbase = qk + (size_t)(n * 96 + h * 16) * COLS;
    const unsigned short* kbase = qk + (size_t)(n * 96 + 48 + h * 16) * COLS;
    for (int tc = p * 32; tc < p * 32 + 32; tc += 8) {
        __syncthreads();
        for (int e = threadIdx.x; e < 16 * 8 * 25; e += 256) {
            int d = e / 200, r = e % 200;
            int tt = r / 25, u = r % 25;
            Qs[d][tt][u] = bf2f(qbase[(size_t)d * COLS + (tc + tt) * 25 + u]);
            Ks[d][tt][u] = bf2f(kbase[(size_t)d * COLS + (tc + tt) * 25 + u]);
        }
        __syncthreads();
#pragma unroll
        for (int q = 0; q < 3; ++q) {
            int e = threadIdx.x + q * 256;
            if (e < 625) {
                int u = e / 25, v = e % 25;
                float a = acc[q];
                for (int tt = 0; tt < 8; ++tt) {
#pragma unroll
                    for (int d = 0; d < 16; ++d)
                        a += Qs[d][tt][u] * Ks[d][tt][v];
                }
                acc[q] = a;
            }
        }
    }
    float* pb = part + ((size_t)p * 384 + nh) * 625;
#pragma unroll
    for (int q = 0; q < 3; ++q) {
        int e = threadIdx.x + q * 256;
        if (e < 625) pb[e] = acc[q];
    }
}

// ---- k2b: combine partials + softmax -> att[n,h,u,v] ----
__global__ __launch_bounds__(64) void k2b_smax(const float* __restrict__ part,
                                               const float* __restrict__ values,
                                               const float* __restrict__ att_bias,
                                               float* __restrict__ att)
{
    int nh = blockIdx.x;
    int h = nh % H_;
    if (threadIdx.x < 25) {
        int u = threadIdx.x;
        float scale = values[h] / 2048.0f;
        float bias = att_bias[h];
        float L[25];
        float m = -1e30f;
        for (int v = 0; v < 25; ++v) {
            size_t idx = (size_t)nh * 625 + u * 25 + v;
            float s = part[idx] + part[384 * 625 + idx] + part[2 * 384 * 625 + idx]
                    + part[3 * 384 * 625 + idx];
            L[v] = s * scale + bias;
            m = fmaxf(m, L[v]);
        }
        float ex[25];
        float s = 0.f;
        for (int v = 0; v < 25; ++v) { ex[v] = expf(L[v] - m); s += ex[v]; }
        float inv = 1.0f / s;
        float* ab = att + (size_t)nh * 625 + u * 25;
        for (int v = 0; v < 25; ++v) ab[v] = ex[v] * inv;
    }
}

// ---- k3: x1 GEMM M=128,K=256 with ON-THE-FLY Tm (fused k_tm) ----
// B taps 0..191: Tm[hc][col] = sum_u xT[t(col)*25+u][c] * att[h][u][v(col)], computed into Bh
// B taps 192..255: xT read directly from staged Xs tile.
__global__ __launch_bounds__(256, 2) void k3_mfma(const unsigned short* __restrict__ w3h,
                                                   const unsigned short* __restrict__ xthi,
                                                   const float* __restrict__ att,
                                                   const float* __restrict__ b3,
                                                   unsigned short* __restrict__ x1hi)
{
    __shared__ unsigned short Ah[128][40], Bh[128][40];
    __shared__ unsigned short Xs[175][72];     // padded: stride 144B (16B-aligned, bank-drift 4)
    __shared__ float As[3][25][26];
    int blk = blockIdx.x;
    int n = blk / 25, ct = blk % 25;
    int c0 = ct * 128;
    int t0 = c0 / 25;
    int xbase = t0 * 25;
    int tid = threadIdx.x, lane = tid & 63, wid = tid >> 6;
    int wm = wid & 1, wn = wid >> 1;
    const unsigned short* xh = xthi + (size_t)n * COLS * 64;

    // stage Xs rows xbase..xbase+174 (guarded) and att
    for (int L = tid; L < 175 * 8; L += 256) {
        int row = L >> 3, g = (L & 7) * 8;
        int rr = xbase + row;
        ushort8 v = (ushort8)0;
        if (rr < 3200) v = *(const ushort8*)&xh[(size_t)rr * 64 + g];
        *(ushort8*)&Xs[row][g] = v;
    }
    const float* ab = att + (size_t)n * 3 * 625;
    for (int e = tid; e < 1875; e += 256) {
        int h = e / 625, r = e % 625;
        As[h][r / 25][r % 25] = ab[e];
    }

    f32x4 acc[4][4];
#pragma unroll
    for (int a = 0; a < 4; ++a)
#pragma unroll
        for (int b = 0; b < 4; ++b) acc[a][b] = (f32x4)0.f;
    int rbase = lane & 15, koff = (lane >> 4) * 8;

    for (int ks = 0; ks < 8; ++ks) {
        __syncthreads();
        for (int L = tid; L < 512; L += 256) {
            int o = L >> 2, g = (L & 3) * 8;
            *(ushort8*)&Ah[o][g] = *(const ushort8*)&w3h[(size_t)o * 256 + ks * 32 + g];
        }
        if (ks < 6) {
            // compute Tm chunk (128 cols x 32 hc) into Bh
#pragma unroll 4
            for (int r = 0; r < 16; ++r) {
                int idx = r * 256 + tid;
                int col = idx >> 5, hcl = idx & 31;
                int hc = ks * 32 + hcl;
                int h = hc >> 6, c = hc & 63;
                int gcol = c0 + col;
                int t = gcol / 25, v = gcol - t * 25;
                int rb = t * 25 - xbase;
                float a = 0.f;
#pragma unroll
                for (int u = 0; u < 25; ++u)
                    a += bf2f(Xs[rb + u][c]) * As[h][u][v];
                Bh[col][hcl] = f2bf_rne(a);
            }
        }
        __syncthreads();
        short8 afh[4], bfh[4];
#pragma unroll
        for (int mb = 0; mb < 4; ++mb)
            afh[mb] = *(const short8*)&Ah[wm * 64 + mb * 16 + rbase][koff];
        if (ks < 6) {
#pragma unroll
            for (int nb = 0; nb < 4; ++nb)
                bfh[nb] = *(const short8*)&Bh[wn * 64 + nb * 16 + rbase][koff];
        } else {
#pragma unroll
            for (int nb = 0; nb < 4; ++nb)
                bfh[nb] = *(const short8*)&Xs[c0 - xbase + wn * 64 + nb * 16 + rbase][(ks - 6) * 32 + koff];
        }
#pragma unroll
        for (int mb = 0; mb < 4; ++mb)
#pragma unroll
            for (int nb = 0; nb < 4; ++nb)
                acc[mb][nb] = __builtin_amdgcn_mfma_f32_16x16x32_bf16(afh[mb], bfh[nb], acc[mb][nb], 0, 0, 0);
    }
#pragma unroll
    for (int mb = 0; mb < 4; ++mb) {
#pragma unroll
        for (int nb = 0; nb < 4; ++nb) {
            int col = c0 + wn * 64 + nb * 16 + (lane & 15);
            int obase = wm * 64 + mb * 16 + (lane >> 4) * 4;
            us4v hv;
#pragma unroll
            for (int r = 0; r < 4; ++r)
                hv[r] = f2bf_rne(lrelu(acc[mb][nb][r] + b3[obase + r]));
            *(us4v*)&x1hi[((size_t)n * COLS + col) * 128 + obase] = hv;
        }
    }
}

// ---- k4: x2 GEMM M=128,K=192 (128 x1 + 64 x) -> x2T bf16 ----
__global__ __launch_bounds__(256, 2) void k4_mfma(const unsigned short* __restrict__ w4h,
                                                   const unsigned short* __restrict__ x1hi,
                                                   const unsigned short* __restrict__ xthi,
                                                   const float* __restrict__ b4,
                                                   unsigned short* __restrict__ x2hi)
{
    __shared__ unsigned short Ah[128][40], Bh[128][40];
    int blk = blockIdx.x;
    int n = blk / 25, ct = blk % 25;
    int c0 = ct * 128;
    int tid = threadIdx.x, lane = tid & 63, wid = tid >> 6;
    int wm = wid & 1, wn = wid >> 1;
    const unsigned short* ph = x1hi + (size_t)n * COLS * 128;
    const unsigned short* xh = xthi + (size_t)n * COLS * 64;
    f32x4 acc[4][4];
#pragma unroll
    for (int a = 0; a < 4; ++a)
#pragma unroll
        for (int b = 0; b < 4; ++b) acc[a][b] = (f32x4)0.f;
    int rbase = lane & 15, koff = (lane >> 4) * 8;

    for (int ks = 0; ks < 6; ++ks) {
        __syncthreads();
        for (int L = tid; L < 512; L += 256) {
            int o = L >> 2, g = (L & 3) * 8;
            *(ushort8*)&Ah[o][g] = *(const ushort8*)&w4h[(size_t)o * 192 + ks * 32 + g];
        }
        for (int L = tid; L < 512; L += 256) {
            int col = L >> 2, g = (L & 3) * 8;
            ushort8 vh;
            if (ks < 4) {
                vh = *(const ushort8*)&ph[(size_t)(c0 + col) * 128 + ks * 32 + g];
            } else {
                vh = *(const ushort8*)&xh[(size_t)(c0 + col) * 64 + (ks - 4) * 32 + g];
            }
            *(ushort8*)&Bh[col][g] = vh;
        }
        __syncthreads();
        short8 afh[4], bfh[4];
#pragma unroll
        for (int mb = 0; mb < 4; ++mb)
            afh[mb] = *(const short8*)&Ah[wm * 64 + mb * 16 + rbase][koff];
#pragma unroll
        for (int nb = 0; nb < 4; ++nb)
            bfh[nb] = *(const short8*)&Bh[wn * 64 + nb * 16 + rbase][koff];
#pragma unroll
        for (int mb = 0; mb < 4; ++mb)
#pragma unroll
            for (int nb = 0; nb < 4; ++nb)
                acc[mb][nb] = __builtin_amdgcn_mfma_f32_16x16x32_bf16(afh[mb], bfh[nb], acc[mb][nb], 0, 0, 0);
    }
#pragma unroll
    for (int mb = 0; mb < 4; ++mb) {
#pragma unroll
        for (int nb = 0; nb < 4; ++nb) {
            int col = c0 + wn * 64 + nb * 16 + (lane & 15);
            int obase = wm * 64 + mb * 16 + (lane >> 4) * 4;
            us4v hv;
#pragma unroll
            for (int r = 0; r < 4; ++r)
                hv[r] = f2bf_rne(lrelu(acc[mb][nb][r] + b4[obase + r]));
            *(us4v*)&x2hi[((size_t)n * COLS + col) * 128 + obase] = hv;
        }
    }
}

// ---- k5: fused temporal(K=7)+rest conv. Double-buffered wide-B in LDS,
//      full 8-tap A register prefetch (issued before B loads), XCD swizzle. ----
__global__ __launch_bounds__(256) void k5_mfma(const unsigned short* __restrict__ wAhi,
                                               const unsigned short* __restrict__ x2hiT,
                                               const float* __restrict__ bcomb,
                                               float* __restrict__ out)
{
    __shared__ unsigned short Bh[2][280][40];   // 44.8 KB

    int bid = blockIdx.x;
    int swz = (bid & 7) * 400 + (bid >> 3);     // 3200 = 8*400, bijective; whole n's per XCD
    int n = swz / 25, ct = swz % 25;
    int c0 = ct * 128;
    int tid = threadIdx.x;
    int lane = tid & 63, wid = tid >> 6;
    int wm = wid & 1, wn = wid >> 1;

    const unsigned short* x2h_n = x2hiT + (size_t)n * 409600;

    f32x4 acc[4][4];
#pragma unroll
    for (int a = 0; a < 4; ++a)
#pragma unroll
        for (int b = 0; b < 4; ++b) acc[a][b] = (f32x4)0.f;

    int rbase = lane & 15;
    int koff = (lane >> 4) * 8;
    int base = c0 - 75;
    int aoff[4];
#pragma unroll
    for (int mb = 0; mb < 4; ++mb)
        aoff[mb] = (wm * 64 + mb * 16 + rbase) * 1024 + koff;

    ushort8 bn[5];
    auto LOADB = [&](int icc) {
#pragma unroll
        for (int j = 0; j < 5; ++j) {
            int L = tid + j * 256;
            ushort8 v = (ushort8)0;
            if (L < 1112) {
                int w = L >> 2, g = (L & 3) * 8;
                int cs = base + w;
                if (cs >= 0 && cs < 3200)
                    v = *(const ushort8*)&x2h_n[(size_t)cs * 128 + icc * 32 + g];
            }
            bn[j] = v;
        }
    };
    auto WRITEB = [&](int buf) {
#pragma unroll
        for (int j = 0; j < 5; ++j) {
            int L = tid + j * 256;
            if (L < 1112) {
                int w = L >> 2, g = (L & 3) * 8;
                *(ushort8*)&Bh[buf][w][g] = bn[j];
            }
        }
    };

    LOADB(0);
    WRITEB(0);
    __syncthreads();

    for (int ic = 0; ic < 4; ++ic) {
        int i0 = ic * 32, cur = ic & 1;
        // full 8-tap A prefetch FIRST (so per-tap vmcnt waits never cover B loads)
        short8 afT[8][4];
#pragma unroll
        for (int t = 0; t < 8; ++t)
#pragma unroll
            for (int mb = 0; mb < 4; ++mb)
                afT[t][mb] = *(const short8*)&wAhi[aoff[mb] + t * 128 + i0];
        if (ic < 3) LOADB(ic + 1);   // issue next-ic B loads; consumed at WRITEB below
#pragma unroll
        for (int tap = 0; tap < 8; ++tap) {
            int wofs = (tap < 7) ? 25 * tap : 75;
            short8 bf[4];
#pragma unroll
            for (int nb = 0; nb < 4; ++nb)
                bf[nb] = *(const short8*)&Bh[cur][wn * 64 + nb * 16 + rbase + wofs][koff];
#pragma unroll
            for (int mb = 0; mb < 4; ++mb)
#pragma unroll
                for (int nb = 0; nb < 4; ++nb)
                    acc[mb][nb] = __builtin_amdgcn_mfma_f32_16x16x32_bf16(afT[tap][mb], bf[nb], acc[mb][nb], 0, 0, 0);
        }
        if (ic < 3) WRITEB(cur ^ 1);
        __syncthreads();
    }
#pragma unroll
    for (int mb = 0; mb < 4; ++mb) {
#pragma unroll
        for (int nb = 0; nb < 4; ++nb) {
            int col = c0 + wn * 64 + nb * 16 + (lane & 15);
#pragma unroll
            for (int r = 0; r < 4; ++r) {
                int o = wm * 64 + mb * 16 + (lane >> 4) * 4 + r;
                float y = acc[mb][nb][r] + bcomb[o];
                out[((size_t)n * 128 + o) * 3200 + col] = lrelu(y);
            }
        }
    }
}

extern "C" void kernel_launch(void* const* d_in, const int* in_sizes, int n_in,
                              void* d_out, int out_size, void* d_ws, size_t ws_size,
                              hipStream_t stream)
{
    const float* x       = (const float*)d_in[0];
    const float* w_qkv   = (const float*)d_in[1];
    const float* b_qkv   = (const float*)d_in[2];
    const float* values  = (const float*)d_in[3];
    const float* att_bias= (const float*)d_in[4];
    const float* w_out   = (const float*)d_in[5];
    const float* b_out   = (const float*)d_in[6];
    const float* g_out   = (const float*)d_in[7];
    const float* be_out  = (const float*)d_in[8];
    const float* m_out   = (const float*)d_in[9];
    const float* v_out   = (const float*)d_in[10];
    const float* w_ff    = (const float*)d_in[11];
    const float* b_ff    = (const float*)d_in[12];
    const float* g_ff    = (const float*)d_in[13];
    const float* be_ff   = (const float*)d_in[14];
    const float* m_ff    = (const float*)d_in[15];
    const float* v_ff    = (const float*)d_in[16];
    const float* w_t     = (const float*)d_in[17];
    const float* b_t     = (const float*)d_in[18];
    const float* g_t     = (const float*)d_in[19];
    const float* be_t    = (const float*)d_in[20];
    const float* m_t     = (const float*)d_in[21];
    const float* v_t     = (const float*)d_in[22];
    const float* w_ress  = (const float*)d_in[23];
    const float* b_ress  = (const float*)d_in[24];
    const float* g_ress  = (const float*)d_in[25];
    const float* be_ress = (const float*)d_in[26];
    const float* m_ress  = (const float*)d_in[27];
    const float* v_ress  = (const float*)d_in[28];
    const float* w_rest  = (const float*)d_in[29];
    const float* b_rest  = (const float*)d_in[30];
    const float* g_rest  = (const float*)d_in[31];
    const float* be_rest = (const float*)d_in[32];
    const float* m_rest  = (const float*)d_in[33];
    const float* v_rest  = (const float*)d_in[34];

    float* ws = (float*)d_ws;
    float* out = (float*)d_out;

    unsigned short* xthi = (unsigned short*)(ws + OFF_XTHI);
    unsigned short* qk   = (unsigned short*)(ws + OFF_BIG);
    float*          part = ws + OFF_PART;
    unsigned short* x2hi = (unsigned short*)(ws + OFF_BIG);
    unsigned short* x1hi = (unsigned short*)out;

    k0_prep<<<128, 256, 0, stream>>>(w_qkv,
        w_out, b_out, g_out, be_out, m_out, v_out,
        w_ff, b_ff, g_ff, be_ff, m_ff, v_ff,
        w_t, b_t, g_t, be_t, m_t, v_t,
        w_ress, b_ress, g_ress, be_ress, m_ress, v_ress,
        w_rest, b_rest, g_rest, be_rest, m_rest, v_rest,
        ws);
    k_xt<<<N_ * T_, 256, 0, stream>>>(x, xthi);
    k1_mfma<<<N_ * 25, 256, 0, stream>>>(
        (const unsigned short*)(ws + OFF_WQHI), xthi, b_qkv, qk);
    k2_att<<<N_ * H_ * 4, 256, 0, stream>>>(qk, part);
    k2b_smax<<<N_ * H_, 64, 0, stream>>>(part, values, att_bias, ws + OFF_ATT);
    k3_mfma<<<N_ * 25, 256, 0, stream>>>(
        (const unsigned short*)(ws + OFF_WA3HI), xthi, ws + OFF_ATT, ws + OFF_B3, x1hi);
    k4_mfma<<<N_ * 25, 256, 0, stream>>>(
        (const unsigned short*)(ws + OFF_WA4HI), x1hi, xthi, ws + OFF_B4, x2hi);
    k5_mfma<<<N_ * 25, 256, 0, stream>>>(
        (const unsigned short*)(ws + OFF_WA5HI), x2hi, ws + OFF_B5, out);
}

// Round 10
// 782.429 us; speedup vs baseline: 1.0622x; 1.0622x over previous
//
#include <hip/hip_runtime.h>

#define N_  128
#define C_  64
#define T_  128
#define V_  25
#define CO_ 128
#define H_  3
#define D_  16

constexpr int COLS = 3200;
constexpr float EPSF = 1e-5f;

typedef __attribute__((ext_vector_type(8))) short short8;
typedef __attribute__((ext_vector_type(8))) unsigned short ushort8;
typedef __attribute__((ext_vector_type(4))) unsigned short us4v;
typedef __attribute__((ext_vector_type(4))) float f32x4;

// ---- workspace layout (float units) ----
constexpr size_t OFF_ATT  = 0;                          // 240,000
constexpr size_t OFF_XTHI = 240000;                     // 13,107,200 fl (26.2M ushorts)
constexpr size_t OFF_BIG  = OFF_XTHI + 13107200;        // time-shared:
//   phase A: qk bf16 [n][96][3200] (19.7M fl) ; part at +20M fl
//   phase B: TmT bf16 [n][3200][192] (39.3M fl)
//   phase C: x2T bf16 [n][3200][128] (26.2M fl)
constexpr size_t BIGF     = 78643200;
constexpr size_t OFF_PART = OFF_BIG + 20000000;         // 960,000 floats (4*384*625)
constexpr size_t OFF_W    = OFF_BIG + BIGF;
constexpr size_t OFF_WQHI  = OFF_W;                     // 96*64 us = 3072 fl
constexpr size_t OFF_WA3HI = OFF_WQHI + 3072;           // 128*256 us = 16384 fl
constexpr size_t OFF_WA4HI = OFF_WA3HI + 16384;         // 128*192 us = 12288 fl
constexpr size_t OFF_WA5HI = OFF_WA4HI + 12288;         // 128*1024 us = 65536 fl
constexpr size_t OFF_B3    = OFF_WA5HI + 65536;
constexpr size_t OFF_B4    = OFF_B3 + 128;
constexpr size_t OFF_B5    = OFF_B4 + 128;

__device__ __forceinline__ float lrelu(float y) { return y >= 0.f ? y : 0.1f * y; }

__device__ __forceinline__ unsigned short f2bf_rne(float f) {
    unsigned int u = __builtin_bit_cast(unsigned int, f);
    u += 0x7FFFu + ((u >> 16) & 1u);
    return (unsigned short)(u >> 16);
}
__device__ __forceinline__ float bf2f(unsigned short b) {
    unsigned int u = ((unsigned int)b) << 16;
    return __builtin_bit_cast(float, u);
}

// ---- K0: BN-fold + bf16 A-operands (single plane) ----
__global__ void k0_prep(const float* __restrict__ w_qkv,
                        const float* __restrict__ w_out, const float* __restrict__ b_out,
                        const float* __restrict__ g_out, const float* __restrict__ be_out,
                        const float* __restrict__ m_out, const float* __restrict__ v_out,
                        const float* __restrict__ w_ff,  const float* __restrict__ b_ff,
                        const float* __restrict__ g_ff,  const float* __restrict__ be_ff,
                        const float* __restrict__ m_ff,  const float* __restrict__ v_ff,
                        const float* __restrict__ w_t,   const float* __restrict__ b_t,
                        const float* __restrict__ g_t,   const float* __restrict__ be_t,
                        const float* __restrict__ m_t,   const float* __restrict__ v_t,
                        const float* __restrict__ w_ress,const float* __restrict__ b_ress,
                        const float* __restrict__ g_ress,const float* __restrict__ be_ress,
                        const float* __restrict__ m_ress,const float* __restrict__ v_ress,
                        const float* __restrict__ w_rest,const float* __restrict__ b_rest,
                        const float* __restrict__ g_rest,const float* __restrict__ be_rest,
                        const float* __restrict__ m_rest,const float* __restrict__ v_rest,
                        float* __restrict__ ws)
{
    int tid = blockIdx.x * blockDim.x + threadIdx.x;
    int np = gridDim.x * blockDim.x;

    unsigned short* wqh = (unsigned short*)(ws + OFF_WQHI);
    for (int idx = tid; idx < 96 * 64; idx += np)
        wqh[idx] = f2bf_rne(w_qkv[idx]);

    unsigned short* w3h = (unsigned short*)(ws + OFF_WA3HI);
    for (int idx = tid; idx < 128 * 256; idx += np) {
        int o = idx >> 8, k = idx & 255;
        float val;
        if (k < 192) {
            float sc = g_out[o] * rsqrtf(v_out[o] + EPSF);
            val = w_out[o * 192 + k] * sc;
        } else {
            float sc = g_ress[o] * rsqrtf(v_ress[o] + EPSF);
            val = w_ress[o * 64 + (k - 192)] * sc;
        }
        w3h[idx] = f2bf_rne(val);
    }

    unsigned short* w4h = (unsigned short*)(ws + OFF_WA4HI);
    for (int idx = tid; idx < 128 * 192; idx += np) {
        int o = idx / 192, k = idx % 192;
        float val;
        if (k < 128) {
            float sc = g_ff[o] * rsqrtf(v_ff[o] + EPSF);
            val = w_ff[o * 128 + k] * sc;
        } else {
            float sc = g_ress[o] * rsqrtf(v_ress[o] + EPSF);
            val = w_ress[o * 64 + (k - 128)] * sc;
        }
        w4h[idx] = f2bf_rne(val);
    }

    unsigned short* w5h = (unsigned short*)(ws + OFF_WA5HI);
    for (int idx = tid; idx < 128 * 1024; idx += np) {
        int o = idx >> 10, kk = idx & 1023;
        int tap = kk >> 7, i = kk & 127;
        float val;
        if (tap < 7) {
            float sc = g_t[o] * rsqrtf(v_t[o] + EPSF);
            val = w_t[((size_t)o * 128 + i) * 7 + tap] * sc;
        } else {
            float sc = g_rest[o] * rsqrtf(v_rest[o] + EPSF);
            val = w_rest[o * 128 + i] * sc;
        }
        w5h[idx] = f2bf_rne(val);
    }

    for (int o = tid; o < 128; o += np) {
        float sco = g_out[o] * rsqrtf(v_out[o] + EPSF);
        float scr = g_ress[o] * rsqrtf(v_ress[o] + EPSF);
        float scf = g_ff[o] * rsqrtf(v_ff[o] + EPSF);
        float sct = g_t[o] * rsqrtf(v_t[o] + EPSF);
        float sce = g_rest[o] * rsqrtf(v_rest[o] + EPSF);
        float bres = (b_ress[o] - m_ress[o]) * scr + be_ress[o];
        ws[OFF_B3 + o] = (b_out[o] - m_out[o]) * sco + be_out[o] + bres;
        ws[OFF_B4 + o] = (b_ff[o] - m_ff[o]) * scf + be_ff[o] + bres;
        ws[OFF_B5 + o] = (b_t[o] - m_t[o]) * sct + be_t[o]
                       + (b_rest[o] - m_rest[o]) * sce + be_rest[o];
    }
}

// ---- k_xt: x[n][c][t][v] -> xT[n][col][64] bf16 ----
__global__ __launch_bounds__(256) void k_xt(const float* __restrict__ x,
                                            unsigned short* __restrict__ xthi)
{
    __shared__ float Xs[64][26];
    int nt = blockIdx.x;
    int n = nt >> 7, t = nt & 127;
    const float* xb = x + ((size_t)n * C_ * T_ + t) * V_;
    for (int e = threadIdx.x; e < 1600; e += 256) {
        int c = e / 25, u = e % 25;
        Xs[c][u] = xb[(size_t)c * (T_ * V_) + u];
    }
    __syncthreads();
    unsigned short* dh = xthi + ((size_t)n * COLS + t * 25) * 64;
    for (int e = threadIdx.x; e < 1600; e += 256) {
        int v = e >> 6, c = e & 63;
        dh[(size_t)v * 64 + c] = f2bf_rne(Xs[c][v]);
    }
}

// ---- k1: qkv GEMM M=96,K=64 -> qk bf16 [n][96][3200] ----
__global__ __launch_bounds__(256, 2) void k1_mfma(const unsigned short* __restrict__ wqh,
                                                   const unsigned short* __restrict__ xthi,
                                                   const float* __restrict__ b_qkv,
                                                   unsigned short* __restrict__ qk)
{
    __shared__ unsigned short Ah[96][40], Bh[128][40];
    int blk = blockIdx.x;
    int n = blk / 25, ct = blk % 25;
    int c0 = ct * 128;
    int tid = threadIdx.x, lane = tid & 63, wid = tid >> 6;
    int wm = wid & 1, wn = wid >> 1;
    const unsigned short* xh = xthi + (size_t)n * COLS * 64;
    f32x4 acc[3][4];
#pragma unroll
    for (int a = 0; a < 3; ++a)
#pragma unroll
        for (int b = 0; b < 4; ++b) acc[a][b] = (f32x4)0.f;
    int rbase = lane & 15, koff = (lane >> 4) * 8;

    for (int ks = 0; ks < 2; ++ks) {
        __syncthreads();
        for (int L = tid; L < 384; L += 256) {
            int o = L >> 2, g = (L & 3) * 8;
            *(ushort8*)&Ah[o][g] = *(const ushort8*)&wqh[(size_t)o * 64 + ks * 32 + g];
        }
        for (int L = tid; L < 512; L += 256) {
            int col = L >> 2, g = (L & 3) * 8;
            size_t src = (size_t)(c0 + col) * 64 + ks * 32 + g;
            *(ushort8*)&Bh[col][g] = *(const ushort8*)&xh[src];
        }
        __syncthreads();
        short8 afh[3], bfh[4];
#pragma unroll
        for (int mb = 0; mb < 3; ++mb)
            afh[mb] = *(const short8*)&Ah[wm * 48 + mb * 16 + rbase][koff];
#pragma unroll
        for (int nb = 0; nb < 4; ++nb)
            bfh[nb] = *(const short8*)&Bh[wn * 64 + nb * 16 + rbase][koff];
#pragma unroll
        for (int mb = 0; mb < 3; ++mb)
#pragma unroll
            for (int nb = 0; nb < 4; ++nb)
                acc[mb][nb] = __builtin_amdgcn_mfma_f32_16x16x32_bf16(afh[mb], bfh[nb], acc[mb][nb], 0, 0, 0);
    }
#pragma unroll
    for (int mb = 0; mb < 3; ++mb) {
#pragma unroll
        for (int nb = 0; nb < 4; ++nb) {
            int col = c0 + wn * 64 + nb * 16 + (lane & 15);
#pragma unroll
            for (int r = 0; r < 4; ++r) {
                int o = wm * 48 + mb * 16 + (lane >> 4) * 4 + r;
                qk[((size_t)n * 96 + o) * COLS + col] = f2bf_rne(acc[mb][nb][r] + b_qkv[o]);
            }
        }
    }
}

// ---- k2: partial attention logits (T split 4-way) -> part[p][nh][u][v] ----
__global__ __launch_bounds__(256) void k2_att(const unsigned short* __restrict__ qk,
                                              float* __restrict__ part)
{
    int blk = blockIdx.x;
    int nh = blk >> 2, p = blk & 3;
    int n = nh / H_, h = nh % H_;
    __shared__ float Qs[D_][8][26];
    __shared__ float Ks[D_][8][26];
    float acc[3] = {0.f, 0.f, 0.f};
    const unsigned short* qbase = qk + (size_t)(n * 96 + h * 16) * COLS;
    const unsigned short* kbase = qk + (size_t)(n * 96 + 48 + h * 16) * COLS;
    for (int tc = p * 32; tc < p * 32 + 32; tc += 8) {
        __syncthreads();
        for (int e = threadIdx.x; e < 16 * 8 * 25; e += 256) {
            int d = e / 200, r = e % 200;
            int tt = r / 25, u = r % 25;
            Qs[d][tt][u] = bf2f(qbase[(size_t)d * COLS + (tc + tt) * 25 + u]);
            Ks[d][tt][u] = bf2f(kbase[(size_t)d * COLS + (tc + tt) * 25 + u]);
        }
        __syncthreads();
#pragma unroll
        for (int q = 0; q < 3; ++q) {
            int e = threadIdx.x + q * 256;
            if (e < 625) {
                int u = e / 25, v = e % 25;
                float a = acc[q];
                for (int tt = 0; tt < 8; ++tt) {
#pragma unroll
                    for (int d = 0; d < 16; ++d)
                        a += Qs[d][tt][u] * Ks[d][tt][v];
                }
                acc[q] = a;
            }
        }
    }
    float* pb = part + ((size_t)p * 384 + nh) * 625;
#pragma unroll
    for (int q = 0; q < 3; ++q) {
        int e = threadIdx.x + q * 256;
        if (e < 625) pb[e] = acc[q];
    }
}

// ---- k2b: combine partials + softmax -> att[n,h,u,v] ----
__global__ __launch_bounds__(64) void k2b_smax(const float* __restrict__ part,
                                               const float* __restrict__ values,
                                               const float* __restrict__ att_bias,
                                               float* __restrict__ att)
{
    int nh = blockIdx.x;
    int h = nh % H_;
    if (threadIdx.x < 25) {
        int u = threadIdx.x;
        float scale = values[h] / 2048.0f;
        float bias = att_bias[h];
        float L[25];
        float m = -1e30f;
        for (int v = 0; v < 25; ++v) {
            size_t idx = (size_t)nh * 625 + u * 25 + v;
            float s = part[idx] + part[384 * 625 + idx] + part[2 * 384 * 625 + idx]
                    + part[3 * 384 * 625 + idx];
            L[v] = s * scale + bias;
            m = fmaxf(m, L[v]);
        }
        float ex[25];
        float s = 0.f;
        for (int v = 0; v < 25; ++v) { ex[v] = expf(L[v] - m); s += ex[v]; }
        float inv = 1.0f / s;
        float* ab = att + (size_t)nh * 625 + u * 25;
        for (int v = 0; v < 25; ++v) ab[v] = ex[v] * inv;
    }
}

// ---- k_tm: Tm[hc][t,v] = sum_u x[c][t,u]*att[h][u][v] -> TmT[n][col][192] bf16 ----
__global__ __launch_bounds__(192) void k_tm(const float* __restrict__ x,
                                            const float* __restrict__ att,
                                            unsigned short* __restrict__ tmhi)
{
    __shared__ float Xs[64][26];
    __shared__ float As[3][25][26];
    int nt = blockIdx.x;
    int n = nt >> 7, t = nt & 127;
    const float* xb = x + ((size_t)n * C_ * T_ + t) * V_;
    for (int e = threadIdx.x; e < 1600; e += 192) {
        int c = e / 25, u = e % 25;
        Xs[c][u] = xb[(size_t)c * (T_ * V_) + u];
    }
    const float* ab = att + (size_t)n * 3 * 625;
    for (int e = threadIdx.x; e < 1875; e += 192) {
        int h = e / 625, r = e % 625;
        As[h][r / 25][r % 25] = ab[e];
    }
    __syncthreads();
    int hc = threadIdx.x;
    int h = hc >> 6, c = hc & 63;
    float xr[25];
#pragma unroll
    for (int u = 0; u < 25; ++u) xr[u] = Xs[c][u];
    unsigned short* dh = tmhi + ((size_t)n * COLS + t * 25) * 192 + hc;
#pragma unroll 5
    for (int v = 0; v < 25; ++v) {
        float a = 0.f;
#pragma unroll
        for (int u = 0; u < 25; ++u) a += xr[u] * As[h][u][v];
        dh[(size_t)v * 192] = f2bf_rne(a);
    }
}

// ---- k3: x1 GEMM M=128,K=256 (192 Tm + 64 x) -> x1T bf16 (in d_out) ----
__global__ __launch_bounds__(256, 2) void k3_mfma(const unsigned short* __restrict__ w3h,
                                                   const unsigned short* __restrict__ tmhi,
                                                   const unsigned short* __restrict__ xthi,
                                                   const float* __restrict__ b3,
                                                   unsigned short* __restrict__ x1hi)
{
    __shared__ unsigned short Ah[128][40], Bh[128][40];
    int blk = blockIdx.x;
    int n = blk / 25, ct = blk % 25;
    int c0 = ct * 128;
    int tid = threadIdx.x, lane = tid & 63, wid = tid >> 6;
    int wm = wid & 1, wn = wid >> 1;
    const unsigned short* th = tmhi + (size_t)n * COLS * 192;
    const unsigned short* xh = xthi + (size_t)n * COLS * 64;
    f32x4 acc[4][4];
#pragma unroll
    for (int a = 0; a < 4; ++a)
#pragma unroll
        for (int b = 0; b < 4; ++b) acc[a][b] = (f32x4)0.f;
    int rbase = lane & 15, koff = (lane >> 4) * 8;

    for (int ks = 0; ks < 8; ++ks) {
        __syncthreads();
        for (int L = tid; L < 512; L += 256) {
            int o = L >> 2, g = (L & 3) * 8;
            *(ushort8*)&Ah[o][g] = *(const ushort8*)&w3h[(size_t)o * 256 + ks * 32 + g];
        }
        for (int L = tid; L < 512; L += 256) {
            int col = L >> 2, g = (L & 3) * 8;
            ushort8 vh;
            if (ks < 6) {
                vh = *(const ushort8*)&th[(size_t)(c0 + col) * 192 + ks * 32 + g];
            } else {
                vh = *(const ushort8*)&xh[(size_t)(c0 + col) * 64 + (ks - 6) * 32 + g];
            }
            *(ushort8*)&Bh[col][g] = vh;
        }
        __syncthreads();
        short8 afh[4], bfh[4];
#pragma unroll
        for (int mb = 0; mb < 4; ++mb)
            afh[mb] = *(const short8*)&Ah[wm * 64 + mb * 16 + rbase][koff];
#pragma unroll
        for (int nb = 0; nb < 4; ++nb)
            bfh[nb] = *(const short8*)&Bh[wn * 64 + nb * 16 + rbase][koff];
#pragma unroll
        for (int mb = 0; mb < 4; ++mb)
#pragma unroll
            for (int nb = 0; nb < 4; ++nb)
                acc[mb][nb] = __builtin_amdgcn_mfma_f32_16x16x32_bf16(afh[mb], bfh[nb], acc[mb][nb], 0, 0, 0);
    }
#pragma unroll
    for (int mb = 0; mb < 4; ++mb) {
#pragma unroll
        for (int nb = 0; nb < 4; ++nb) {
            int col = c0 + wn * 64 + nb * 16 + (lane & 15);
            int obase = wm * 64 + mb * 16 + (lane >> 4) * 4;
            us4v hv;
#pragma unroll
            for (int r = 0; r < 4; ++r)
                hv[r] = f2bf_rne(lrelu(acc[mb][nb][r] + b3[obase + r]));
            *(us4v*)&x1hi[((size_t)n * COLS + col) * 128 + obase] = hv;
        }
    }
}

// ---- k4: x2 GEMM M=128,K=192 (128 x1 + 64 x) -> x2T bf16 ----
__global__ __launch_bounds__(256, 2) void k4_mfma(const unsigned short* __restrict__ w4h,
                                                   const unsigned short* __restrict__ x1hi,
                                                   const unsigned short* __restrict__ xthi,
                                                   const float* __restrict__ b4,
                                                   unsigned short* __restrict__ x2hi)
{
    __shared__ unsigned short Ah[128][40], Bh[128][40];
    int blk = blockIdx.x;
    int n = blk / 25, ct = blk % 25;
    int c0 = ct * 128;
    int tid = threadIdx.x, lane = tid & 63, wid = tid >> 6;
    int wm = wid & 1, wn = wid >> 1;
    const unsigned short* ph = x1hi + (size_t)n * COLS * 128;
    const unsigned short* xh = xthi + (size_t)n * COLS * 64;
    f32x4 acc[4][4];
#pragma unroll
    for (int a = 0; a < 4; ++a)
#pragma unroll
        for (int b = 0; b < 4; ++b) acc[a][b] = (f32x4)0.f;
    int rbase = lane & 15, koff = (lane >> 4) * 8;

    for (int ks = 0; ks < 6; ++ks) {
        __syncthreads();
        for (int L = tid; L < 512; L += 256) {
            int o = L >> 2, g = (L & 3) * 8;
            *(ushort8*)&Ah[o][g] = *(const ushort8*)&w4h[(size_t)o * 192 + ks * 32 + g];
        }
        for (int L = tid; L < 512; L += 256) {
            int col = L >> 2, g = (L & 3) * 8;
            ushort8 vh;
            if (ks < 4) {
                vh = *(const ushort8*)&ph[(size_t)(c0 + col) * 128 + ks * 32 + g];
            } else {
                vh = *(const ushort8*)&xh[(size_t)(c0 + col) * 64 + (ks - 4) * 32 + g];
            }
            *(ushort8*)&Bh[col][g] = vh;
        }
        __syncthreads();
        short8 afh[4], bfh[4];
#pragma unroll
        for (int mb = 0; mb < 4; ++mb)
            afh[mb] = *(const short8*)&Ah[wm * 64 + mb * 16 + rbase][koff];
#pragma unroll
        for (int nb = 0; nb < 4; ++nb)
            bfh[nb] = *(const short8*)&Bh[wn * 64 + nb * 16 + rbase][koff];
#pragma unroll
        for (int mb = 0; mb < 4; ++mb)
#pragma unroll
            for (int nb = 0; nb < 4; ++nb)
                acc[mb][nb] = __builtin_amdgcn_mfma_f32_16x16x32_bf16(afh[mb], bfh[nb], acc[mb][nb], 0, 0, 0);
    }
#pragma unroll
    for (int mb = 0; mb < 4; ++mb) {
#pragma unroll
        for (int nb = 0; nb < 4; ++nb) {
            int col = c0 + wn * 64 + nb * 16 + (lane & 15);
            int obase = wm * 64 + mb * 16 + (lane >> 4) * 4;
            us4v hv;
#pragma unroll
            for (int r = 0; r < 4; ++r)
                hv[r] = f2bf_rne(lrelu(acc[mb][nb][r] + b4[obase + r]));
            *(us4v*)&x2hi[((size_t)n * COLS + col) * 128 + obase] = hv;
        }
    }
}

// ---- k5: fused temporal(K=7)+rest conv. Double-buffered wide-B in LDS,
//      full 8-tap A register prefetch (issued before B loads), XCD swizzle. ----
__global__ __launch_bounds__(256) void k5_mfma(const unsigned short* __restrict__ wAhi,
                                               const unsigned short* __restrict__ x2hiT,
                                               const float* __restrict__ bcomb,
                                               float* __restrict__ out)
{
    __shared__ unsigned short Bh[2][280][40];   // 44.8 KB

    int bid = blockIdx.x;
    int swz = (bid & 7) * 400 + (bid >> 3);     // 3200 = 8*400, bijective; whole n's per XCD
    int n = swz / 25, ct = swz % 25;
    int c0 = ct * 128;
    int tid = threadIdx.x;
    int lane = tid & 63, wid = tid >> 6;
    int wm = wid & 1, wn = wid >> 1;

    const unsigned short* x2h_n = x2hiT + (size_t)n * 409600;

    f32x4 acc[4][4];
#pragma unroll
    for (int a = 0; a < 4; ++a)
#pragma unroll
        for (int b = 0; b < 4; ++b) acc[a][b] = (f32x4)0.f;

    int rbase = lane & 15;
    int koff = (lane >> 4) * 8;
    int base = c0 - 75;
    int aoff[4];
#pragma unroll
    for (int mb = 0; mb < 4; ++mb)
        aoff[mb] = (wm * 64 + mb * 16 + rbase) * 1024 + koff;

    ushort8 bn[5];
    auto LOADB = [&](int icc) {
#pragma unroll
        for (int j = 0; j < 5; ++j) {
            int L = tid + j * 256;
            ushort8 v = (ushort8)0;
            if (L < 1112) {
                int w = L >> 2, g = (L & 3) * 8;
                int cs = base + w;
                if (cs >= 0 && cs < 3200)
                    v = *(const ushort8*)&x2h_n[(size_t)cs * 128 + icc * 32 + g];
            }
            bn[j] = v;
        }
    };
    auto WRITEB = [&](int buf) {
#pragma unroll
        for (int j = 0; j < 5; ++j) {
            int L = tid + j * 256;
            if (L < 1112) {
                int w = L >> 2, g = (L & 3) * 8;
                *(ushort8*)&Bh[buf][w][g] = bn[j];
            }
        }
    };

    LOADB(0);
    WRITEB(0);
    __syncthreads();

    for (int ic = 0; ic < 4; ++ic) {
        int i0 = ic * 32, cur = ic & 1;
        short8 afT[8][4];
#pragma unroll
        for (int t = 0; t < 8; ++t)
#pragma unroll
            for (int mb = 0; mb < 4; ++mb)
                afT[t][mb] = *(const short8*)&wAhi[aoff[mb] + t * 128 + i0];
        if (ic < 3) LOADB(ic + 1);
#pragma unroll
        for (int tap = 0; tap < 8; ++tap) {
            int wofs = (tap < 7) ? 25 * tap : 75;
            short8 bf[4];
#pragma unroll
            for (int nb = 0; nb < 4; ++nb)
                bf[nb] = *(const short8*)&Bh[cur][wn * 64 + nb * 16 + rbase + wofs][koff];
#pragma unroll
            for (int mb = 0; mb < 4; ++mb)
#pragma unroll
                for (int nb = 0; nb < 4; ++nb)
                    acc[mb][nb] = __builtin_amdgcn_mfma_f32_16x16x32_bf16(afT[tap][mb], bf[nb], acc[mb][nb], 0, 0, 0);
        }
        if (ic < 3) WRITEB(cur ^ 1);
        __syncthreads();
    }
#pragma unroll
    for (int mb = 0; mb < 4; ++mb) {
#pragma unroll
        for (int nb = 0; nb < 4; ++nb) {
            int col = c0 + wn * 64 + nb * 16 + (lane & 15);
#pragma unroll
            for (int r = 0; r < 4; ++r) {
                int o = wm * 64 + mb * 16 + (lane >> 4) * 4 + r;
                float y = acc[mb][nb][r] + bcomb[o];
                out[((size_t)n * 128 + o) * 3200 + col] = lrelu(y);
            }
        }
    }
}

extern "C" void kernel_launch(void* const* d_in, const int* in_sizes, int n_in,
                              void* d_out, int out_size, void* d_ws, size_t ws_size,
                              hipStream_t stream)
{
    const float* x       = (const float*)d_in[0];
    const float* w_qkv   = (const float*)d_in[1];
    const float* b_qkv   = (const float*)d_in[2];
    const float* values  = (const float*)d_in[3];
    const float* att_bias= (const float*)d_in[4];
    const float* w_out   = (const float*)d_in[5];
    const float* b_out   = (const float*)d_in[6];
    const float* g_out   = (const float*)d_in[7];
    const float* be_out  = (const float*)d_in[8];
    const float* m_out   = (const float*)d_in[9];
    const float* v_out   = (const float*)d_in[10];
    const float* w_ff    = (const float*)d_in[11];
    const float* b_ff    = (const float*)d_in[12];
    const float* g_ff    = (const float*)d_in[13];
    const float* be_ff   = (const float*)d_in[14];
    const float* m_ff    = (const float*)d_in[15];
    const float* v_ff    = (const float*)d_in[16];
    const float* w_t     = (const float*)d_in[17];
    const float* b_t     = (const float*)d_in[18];
    const float* g_t     = (const float*)d_in[19];
    const float* be_t    = (const float*)d_in[20];
    const float* m_t     = (const float*)d_in[21];
    const float* v_t     = (const float*)d_in[22];
    const float* w_ress  = (const float*)d_in[23];
    const float* b_ress  = (const float*)d_in[24];
    const float* g_ress  = (const float*)d_in[25];
    const float* be_ress = (const float*)d_in[26];
    const float* m_ress  = (const float*)d_in[27];
    const float* v_ress  = (const float*)d_in[28];
    const float* w_rest  = (const float*)d_in[29];
    const float* b_rest  = (const float*)d_in[30];
    const float* g_rest  = (const float*)d_in[31];
    const float* be_rest = (const float*)d_in[32];
    const float* m_rest  = (const float*)d_in[33];
    const float* v_rest  = (const float*)d_in[34];

    float* ws = (float*)d_ws;
    float* out = (float*)d_out;

    unsigned short* xthi = (unsigned short*)(ws + OFF_XTHI);
    unsigned short* qk   = (unsigned short*)(ws + OFF_BIG);
    float*          part = ws + OFF_PART;
    unsigned short* tmhi = (unsigned short*)(ws + OFF_BIG);
    unsigned short* x2hi = (unsigned short*)(ws + OFF_BIG);
    unsigned short* x1hi = (unsigned short*)out;

    k0_prep<<<128, 256, 0, stream>>>(w_qkv,
        w_out, b_out, g_out, be_out, m_out, v_out,
        w_ff, b_ff, g_ff, be_ff, m_ff, v_ff,
        w_t, b_t, g_t, be_t, m_t, v_t,
        w_ress, b_ress, g_ress, be_ress, m_ress, v_ress,
        w_rest, b_rest, g_rest, be_rest, m_rest, v_rest,
        ws);
    k_xt<<<N_ * T_, 256, 0, stream>>>(x, xthi);
    k1_mfma<<<N_ * 25, 256, 0, stream>>>(
        (const unsigned short*)(ws + OFF_WQHI), xthi, b_qkv, qk);
    k2_att<<<N_ * H_ * 4, 256, 0, stream>>>(qk, part);
    k2b_smax<<<N_ * H_, 64, 0, stream>>>(part, values, att_bias, ws + OFF_ATT);
    k_tm<<<N_ * T_, 192, 0, stream>>>(x, ws + OFF_ATT, tmhi);
    k3_mfma<<<N_ * 25, 256, 0, stream>>>(
        (const unsigned short*)(ws + OFF_WA3HI), tmhi, xthi, ws + OFF_B3, x1hi);
    k4_mfma<<<N_ * 25, 256, 0, stream>>>(
        (const unsigned short*)(ws + OFF_WA4HI), x1hi, xthi, ws + OFF_B4, x2hi);
    k5_mfma<<<N_ * 25, 256, 0, stream>>>(
        (const unsigned short*)(ws + OFF_WA5HI), x2hi, ws + OFF_B5, out);
}

// Round 11
// 763.985 us; speedup vs baseline: 1.0878x; 1.0241x over previous
//
#include <hip/hip_runtime.h>

#define N_  128
#define C_  64
#define T_  128
#define V_  25
#define CO_ 128
#define H_  3
#define D_  16

constexpr int COLS = 3200;
constexpr float EPSF = 1e-5f;

typedef __attribute__((ext_vector_type(8))) short short8;
typedef __attribute__((ext_vector_type(8))) unsigned short ushort8;
typedef __attribute__((ext_vector_type(4))) unsigned short us4v;
typedef __attribute__((ext_vector_type(4))) float f32x4;

// ---- workspace layout (float units) ----
constexpr size_t OFF_ATT  = 0;                          // 240,000
constexpr size_t OFF_XTHI = 240000;                     // 13,107,200 fl (26.2M ushorts)
constexpr size_t OFF_BIG  = OFF_XTHI + 13107200;        // time-shared:
//   phase A: qk bf16 [n][96][3200] (19.7M fl) ; part at +20M fl
//   phase B: TmT bf16 [n][3200][192] (39.3M fl)
//   phase C: x2T bf16 [n][3200][128] (26.2M fl)
constexpr size_t BIGF     = 78643200;
constexpr size_t OFF_PART = OFF_BIG + 20000000;         // 960,000 floats (4*384*625)
constexpr size_t OFF_W    = OFF_BIG + BIGF;
constexpr size_t OFF_WQHI  = OFF_W;                     // 96*64 us = 3072 fl
constexpr size_t OFF_WA3HI = OFF_WQHI + 3072;           // 128*256 us = 16384 fl
constexpr size_t OFF_WA4HI = OFF_WA3HI + 16384;         // 128*192 us = 12288 fl
constexpr size_t OFF_WA5HI = OFF_WA4HI + 12288;         // 128*1024 us = 65536 fl
constexpr size_t OFF_B3    = OFF_WA5HI + 65536;
constexpr size_t OFF_B4    = OFF_B3 + 128;
constexpr size_t OFF_B5    = OFF_B4 + 128;

__device__ __forceinline__ float lrelu(float y) { return y >= 0.f ? y : 0.1f * y; }

__device__ __forceinline__ unsigned short f2bf_rne(float f) {
    unsigned int u = __builtin_bit_cast(unsigned int, f);
    u += 0x7FFFu + ((u >> 16) & 1u);
    return (unsigned short)(u >> 16);
}
__device__ __forceinline__ float bf2f(unsigned short b) {
    unsigned int u = ((unsigned int)b) << 16;
    return __builtin_bit_cast(float, u);
}

// ---- K0: BN-fold + bf16 A-operands (single plane) ----
__global__ void k0_prep(const float* __restrict__ w_qkv,
                        const float* __restrict__ w_out, const float* __restrict__ b_out,
                        const float* __restrict__ g_out, const float* __restrict__ be_out,
                        const float* __restrict__ m_out, const float* __restrict__ v_out,
                        const float* __restrict__ w_ff,  const float* __restrict__ b_ff,
                        const float* __restrict__ g_ff,  const float* __restrict__ be_ff,
                        const float* __restrict__ m_ff,  const float* __restrict__ v_ff,
                        const float* __restrict__ w_t,   const float* __restrict__ b_t,
                        const float* __restrict__ g_t,   const float* __restrict__ be_t,
                        const float* __restrict__ m_t,   const float* __restrict__ v_t,
                        const float* __restrict__ w_ress,const float* __restrict__ b_ress,
                        const float* __restrict__ g_ress,const float* __restrict__ be_ress,
                        const float* __restrict__ m_ress,const float* __restrict__ v_ress,
                        const float* __restrict__ w_rest,const float* __restrict__ b_rest,
                        const float* __restrict__ g_rest,const float* __restrict__ be_rest,
                        const float* __restrict__ m_rest,const float* __restrict__ v_rest,
                        float* __restrict__ ws)
{
    int tid = blockIdx.x * blockDim.x + threadIdx.x;
    int np = gridDim.x * blockDim.x;

    unsigned short* wqh = (unsigned short*)(ws + OFF_WQHI);
    for (int idx = tid; idx < 96 * 64; idx += np)
        wqh[idx] = f2bf_rne(w_qkv[idx]);

    unsigned short* w3h = (unsigned short*)(ws + OFF_WA3HI);
    for (int idx = tid; idx < 128 * 256; idx += np) {
        int o = idx >> 8, k = idx & 255;
        float val;
        if (k < 192) {
            float sc = g_out[o] * rsqrtf(v_out[o] + EPSF);
            val = w_out[o * 192 + k] * sc;
        } else {
            float sc = g_ress[o] * rsqrtf(v_ress[o] + EPSF);
            val = w_ress[o * 64 + (k - 192)] * sc;
        }
        w3h[idx] = f2bf_rne(val);
    }

    unsigned short* w4h = (unsigned short*)(ws + OFF_WA4HI);
    for (int idx = tid; idx < 128 * 192; idx += np) {
        int o = idx / 192, k = idx % 192;
        float val;
        if (k < 128) {
            float sc = g_ff[o] * rsqrtf(v_ff[o] + EPSF);
            val = w_ff[o * 128 + k] * sc;
        } else {
            float sc = g_ress[o] * rsqrtf(v_ress[o] + EPSF);
            val = w_ress[o * 64 + (k - 128)] * sc;
        }
        w4h[idx] = f2bf_rne(val);
    }

    unsigned short* w5h = (unsigned short*)(ws + OFF_WA5HI);
    for (int idx = tid; idx < 128 * 1024; idx += np) {
        int o = idx >> 10, kk = idx & 1023;
        int tap = kk >> 7, i = kk & 127;
        float val;
        if (tap < 7) {
            float sc = g_t[o] * rsqrtf(v_t[o] + EPSF);
            val = w_t[((size_t)o * 128 + i) * 7 + tap] * sc;
        } else {
            float sc = g_rest[o] * rsqrtf(v_rest[o] + EPSF);
            val = w_rest[o * 128 + i] * sc;
        }
        w5h[idx] = f2bf_rne(val);
    }

    for (int o = tid; o < 128; o += np) {
        float sco = g_out[o] * rsqrtf(v_out[o] + EPSF);
        float scr = g_ress[o] * rsqrtf(v_ress[o] + EPSF);
        float scf = g_ff[o] * rsqrtf(v_ff[o] + EPSF);
        float sct = g_t[o] * rsqrtf(v_t[o] + EPSF);
        float sce = g_rest[o] * rsqrtf(v_rest[o] + EPSF);
        float bres = (b_ress[o] - m_ress[o]) * scr + be_ress[o];
        ws[OFF_B3 + o] = (b_out[o] - m_out[o]) * sco + be_out[o] + bres;
        ws[OFF_B4 + o] = (b_ff[o] - m_ff[o]) * scf + be_ff[o] + bres;
        ws[OFF_B5 + o] = (b_t[o] - m_t[o]) * sct + be_t[o]
                       + (b_rest[o] - m_rest[o]) * sce + be_rest[o];
    }
}

// ---- k_xt: x[n][c][t][v] -> xT[n][col][64] bf16 ----
__global__ __launch_bounds__(256) void k_xt(const float* __restrict__ x,
                                            unsigned short* __restrict__ xthi)
{
    __shared__ float Xs[64][26];
    int nt = blockIdx.x;
    int n = nt >> 7, t = nt & 127;
    const float* xb = x + ((size_t)n * C_ * T_ + t) * V_;
    for (int e = threadIdx.x; e < 1600; e += 256) {
        int c = e / 25, u = e % 25;
        Xs[c][u] = xb[(size_t)c * (T_ * V_) + u];
    }
    __syncthreads();
    unsigned short* dh = xthi + ((size_t)n * COLS + t * 25) * 64;
    for (int e = threadIdx.x; e < 1600; e += 256) {
        int v = e >> 6, c = e & 63;
        dh[(size_t)v * 64 + c] = f2bf_rne(Xs[c][v]);
    }
}

// ---- k1: qkv GEMM M=96,K=64 -> qk bf16 [n][96][3200] ----
__global__ __launch_bounds__(256, 2) void k1_mfma(const unsigned short* __restrict__ wqh,
                                                   const unsigned short* __restrict__ xthi,
                                                   const float* __restrict__ b_qkv,
                                                   unsigned short* __restrict__ qk)
{
    __shared__ unsigned short Ah[96][40], Bh[128][40];
    int blk = blockIdx.x;
    int n = blk / 25, ct = blk % 25;
    int c0 = ct * 128;
    int tid = threadIdx.x, lane = tid & 63, wid = tid >> 6;
    int wm = wid & 1, wn = wid >> 1;
    const unsigned short* xh = xthi + (size_t)n * COLS * 64;
    f32x4 acc[3][4];
#pragma unroll
    for (int a = 0; a < 3; ++a)
#pragma unroll
        for (int b = 0; b < 4; ++b) acc[a][b] = (f32x4)0.f;
    int rbase = lane & 15, koff = (lane >> 4) * 8;

    for (int ks = 0; ks < 2; ++ks) {
        __syncthreads();
        for (int L = tid; L < 384; L += 256) {
            int o = L >> 2, g = (L & 3) * 8;
            *(ushort8*)&Ah[o][g] = *(const ushort8*)&wqh[(size_t)o * 64 + ks * 32 + g];
        }
        for (int L = tid; L < 512; L += 256) {
            int col = L >> 2, g = (L & 3) * 8;
            size_t src = (size_t)(c0 + col) * 64 + ks * 32 + g;
            *(ushort8*)&Bh[col][g] = *(const ushort8*)&xh[src];
        }
        __syncthreads();
        short8 afh[3], bfh[4];
#pragma unroll
        for (int mb = 0; mb < 3; ++mb)
            afh[mb] = *(const short8*)&Ah[wm * 48 + mb * 16 + rbase][koff];
#pragma unroll
        for (int nb = 0; nb < 4; ++nb)
            bfh[nb] = *(const short8*)&Bh[wn * 64 + nb * 16 + rbase][koff];
#pragma unroll
        for (int mb = 0; mb < 3; ++mb)
#pragma unroll
            for (int nb = 0; nb < 4; ++nb)
                acc[mb][nb] = __builtin_amdgcn_mfma_f32_16x16x32_bf16(afh[mb], bfh[nb], acc[mb][nb], 0, 0, 0);
    }
#pragma unroll
    for (int mb = 0; mb < 3; ++mb) {
#pragma unroll
        for (int nb = 0; nb < 4; ++nb) {
            int col = c0 + wn * 64 + nb * 16 + (lane & 15);
#pragma unroll
            for (int r = 0; r < 4; ++r) {
                int o = wm * 48 + mb * 16 + (lane >> 4) * 4 + r;
                qk[((size_t)n * 96 + o) * COLS + col] = f2bf_rne(acc[mb][nb][r] + b_qkv[o]);
            }
        }
    }
}

// ---- k2: partial attention logits (T split 4-way) -> part[p][nh][u][v] ----
__global__ __launch_bounds__(256) void k2_att(const unsigned short* __restrict__ qk,
                                              float* __restrict__ part)
{
    int blk = blockIdx.x;
    int nh = blk >> 2, p = blk & 3;
    int n = nh / H_, h = nh % H_;
    __shared__ float Qs[D_][8][26];
    __shared__ float Ks[D_][8][26];
    float acc[3] = {0.f, 0.f, 0.f};
    const unsigned short* qbase = qk + (size_t)(n * 96 + h * 16) * COLS;
    const unsigned short* kbase = qk + (size_t)(n * 96 + 48 + h * 16) * COLS;
    for (int tc = p * 32; tc < p * 32 + 32; tc += 8) {
        __syncthreads();
        for (int e = threadIdx.x; e < 16 * 8 * 25; e += 256) {
            int d = e / 200, r = e % 200;
            int tt = r / 25, u = r % 25;
            Qs[d][tt][u] = bf2f(qbase[(size_t)d * COLS + (tc + tt) * 25 + u]);
            Ks[d][tt][u] = bf2f(kbase[(size_t)d * COLS + (tc + tt) * 25 + u]);
        }
        __syncthreads();
#pragma unroll
        for (int q = 0; q < 3; ++q) {
            int e = threadIdx.x + q * 256;
            if (e < 625) {
                int u = e / 25, v = e % 25;
                float a = acc[q];
                for (int tt = 0; tt < 8; ++tt) {
#pragma unroll
                    for (int d = 0; d < 16; ++d)
                        a += Qs[d][tt][u] * Ks[d][tt][v];
                }
                acc[q] = a;
            }
        }
    }
    float* pb = part + ((size_t)p * 384 + nh) * 625;
#pragma unroll
    for (int q = 0; q < 3; ++q) {
        int e = threadIdx.x + q * 256;
        if (e < 625) pb[e] = acc[q];
    }
}

// ---- k2b: combine partials + softmax -> att[n,h,u,v] ----
__global__ __launch_bounds__(64) void k2b_smax(const float* __restrict__ part,
                                               const float* __restrict__ values,
                                               const float* __restrict__ att_bias,
                                               float* __restrict__ att)
{
    int nh = blockIdx.x;
    int h = nh % H_;
    if (threadIdx.x < 25) {
        int u = threadIdx.x;
        float scale = values[h] / 2048.0f;
        float bias = att_bias[h];
        float L[25];
        float m = -1e30f;
        for (int v = 0; v < 25; ++v) {
            size_t idx = (size_t)nh * 625 + u * 25 + v;
            float s = part[idx] + part[384 * 625 + idx] + part[2 * 384 * 625 + idx]
                    + part[3 * 384 * 625 + idx];
            L[v] = s * scale + bias;
            m = fmaxf(m, L[v]);
        }
        float ex[25];
        float s = 0.f;
        for (int v = 0; v < 25; ++v) { ex[v] = expf(L[v] - m); s += ex[v]; }
        float inv = 1.0f / s;
        float* ab = att + (size_t)nh * 625 + u * 25;
        for (int v = 0; v < 25; ++v) ab[v] = ex[v] * inv;
    }
}

// ---- k_tm: Tm[hc][t,v] = sum_u x[c][t,u]*att[h][u][v] -> TmT[n][col][192] bf16 ----
__global__ __launch_bounds__(192) void k_tm(const float* __restrict__ x,
                                            const float* __restrict__ att,
                                            unsigned short* __restrict__ tmhi)
{
    __shared__ float Xs[64][26];
    __shared__ float As[3][25][26];
    int nt = blockIdx.x;
    int n = nt >> 7, t = nt & 127;
    const float* xb = x + ((size_t)n * C_ * T_ + t) * V_;
    for (int e = threadIdx.x; e < 1600; e += 192) {
        int c = e / 25, u = e % 25;
        Xs[c][u] = xb[(size_t)c * (T_ * V_) + u];
    }
    const float* ab = att + (size_t)n * 3 * 625;
    for (int e = threadIdx.x; e < 1875; e += 192) {
        int h = e / 625, r = e % 625;
        As[h][r / 25][r % 25] = ab[e];
    }
    __syncthreads();
    int hc = threadIdx.x;
    int h = hc >> 6, c = hc & 63;
    float xr[25];
#pragma unroll
    for (int u = 0; u < 25; ++u) xr[u] = Xs[c][u];
    unsigned short* dh = tmhi + ((size_t)n * COLS + t * 25) * 192 + hc;
#pragma unroll 5
    for (int v = 0; v < 25; ++v) {
        float a = 0.f;
#pragma unroll
        for (int u = 0; u < 25; ++u) a += xr[u] * As[h][u][v];
        dh[(size_t)v * 192] = f2bf_rne(a);
    }
}

// ---- k3: x1 GEMM M=128,K=256 (192 Tm + 64 x) -> x1T bf16 (in d_out) ----
__global__ __launch_bounds__(256, 2) void k3_mfma(const unsigned short* __restrict__ w3h,
                                                   const unsigned short* __restrict__ tmhi,
                                                   const unsigned short* __restrict__ xthi,
                                                   const float* __restrict__ b3,
                                                   unsigned short* __restrict__ x1hi)
{
    __shared__ unsigned short Ah[128][40], Bh[128][40];
    int blk = blockIdx.x;
    int n = blk / 25, ct = blk % 25;
    int c0 = ct * 128;
    int tid = threadIdx.x, lane = tid & 63, wid = tid >> 6;
    int wm = wid & 1, wn = wid >> 1;
    const unsigned short* th = tmhi + (size_t)n * COLS * 192;
    const unsigned short* xh = xthi + (size_t)n * COLS * 64;
    f32x4 acc[4][4];
#pragma unroll
    for (int a = 0; a < 4; ++a)
#pragma unroll
        for (int b = 0; b < 4; ++b) acc[a][b] = (f32x4)0.f;
    int rbase = lane & 15, koff = (lane >> 4) * 8;

    for (int ks = 0; ks < 8; ++ks) {
        __syncthreads();
        for (int L = tid; L < 512; L += 256) {
            int o = L >> 2, g = (L & 3) * 8;
            *(ushort8*)&Ah[o][g] = *(const ushort8*)&w3h[(size_t)o * 256 + ks * 32 + g];
        }
        for (int L = tid; L < 512; L += 256) {
            int col = L >> 2, g = (L & 3) * 8;
            ushort8 vh;
            if (ks < 6) {
                vh = *(const ushort8*)&th[(size_t)(c0 + col) * 192 + ks * 32 + g];
            } else {
                vh = *(const ushort8*)&xh[(size_t)(c0 + col) * 64 + (ks - 6) * 32 + g];
            }
            *(ushort8*)&Bh[col][g] = vh;
        }
        __syncthreads();
        short8 afh[4], bfh[4];
#pragma unroll
        for (int mb = 0; mb < 4; ++mb)
            afh[mb] = *(const short8*)&Ah[wm * 64 + mb * 16 + rbase][koff];
#pragma unroll
        for (int nb = 0; nb < 4; ++nb)
            bfh[nb] = *(const short8*)&Bh[wn * 64 + nb * 16 + rbase][koff];
#pragma unroll
        for (int mb = 0; mb < 4; ++mb)
#pragma unroll
            for (int nb = 0; nb < 4; ++nb)
                acc[mb][nb] = __builtin_amdgcn_mfma_f32_16x16x32_bf16(afh[mb], bfh[nb], acc[mb][nb], 0, 0, 0);
    }
#pragma unroll
    for (int mb = 0; mb < 4; ++mb) {
#pragma unroll
        for (int nb = 0; nb < 4; ++nb) {
            int col = c0 + wn * 64 + nb * 16 + (lane & 15);
            int obase = wm * 64 + mb * 16 + (lane >> 4) * 4;
            us4v hv;
#pragma unroll
            for (int r = 0; r < 4; ++r)
                hv[r] = f2bf_rne(lrelu(acc[mb][nb][r] + b3[obase + r]));
            *(us4v*)&x1hi[((size_t)n * COLS + col) * 128 + obase] = hv;
        }
    }
}

// ---- k4: x2 GEMM M=128,K=192 (128 x1 + 64 x) -> x2T bf16 ----
__global__ __launch_bounds__(256, 2) void k4_mfma(const unsigned short* __restrict__ w4h,
                                                   const unsigned short* __restrict__ x1hi,
                                                   const unsigned short* __restrict__ xthi,
                                                   const float* __restrict__ b4,
                                                   unsigned short* __restrict__ x2hi)
{
    __shared__ unsigned short Ah[128][40], Bh[128][40];
    int blk = blockIdx.x;
    int n = blk / 25, ct = blk % 25;
    int c0 = ct * 128;
    int tid = threadIdx.x, lane = tid & 63, wid = tid >> 6;
    int wm = wid & 1, wn = wid >> 1;
    const unsigned short* ph = x1hi + (size_t)n * COLS * 128;
    const unsigned short* xh = xthi + (size_t)n * COLS * 64;
    f32x4 acc[4][4];
#pragma unroll
    for (int a = 0; a < 4; ++a)
#pragma unroll
        for (int b = 0; b < 4; ++b) acc[a][b] = (f32x4)0.f;
    int rbase = lane & 15, koff = (lane >> 4) * 8;

    for (int ks = 0; ks < 6; ++ks) {
        __syncthreads();
        for (int L = tid; L < 512; L += 256) {
            int o = L >> 2, g = (L & 3) * 8;
            *(ushort8*)&Ah[o][g] = *(const ushort8*)&w4h[(size_t)o * 192 + ks * 32 + g];
        }
        for (int L = tid; L < 512; L += 256) {
            int col = L >> 2, g = (L & 3) * 8;
            ushort8 vh;
            if (ks < 4) {
                vh = *(const ushort8*)&ph[(size_t)(c0 + col) * 128 + ks * 32 + g];
            } else {
                vh = *(const ushort8*)&xh[(size_t)(c0 + col) * 64 + (ks - 4) * 32 + g];
            }
            *(ushort8*)&Bh[col][g] = vh;
        }
        __syncthreads();
        short8 afh[4], bfh[4];
#pragma unroll
        for (int mb = 0; mb < 4; ++mb)
            afh[mb] = *(const short8*)&Ah[wm * 64 + mb * 16 + rbase][koff];
#pragma unroll
        for (int nb = 0; nb < 4; ++nb)
            bfh[nb] = *(const short8*)&Bh[wn * 64 + nb * 16 + rbase][koff];
#pragma unroll
        for (int mb = 0; mb < 4; ++mb)
#pragma unroll
            for (int nb = 0; nb < 4; ++nb)
                acc[mb][nb] = __builtin_amdgcn_mfma_f32_16x16x32_bf16(afh[mb], bfh[nb], acc[mb][nb], 0, 0, 0);
    }
#pragma unroll
    for (int mb = 0; mb < 4; ++mb) {
#pragma unroll
        for (int nb = 0; nb < 4; ++nb) {
            int col = c0 + wn * 64 + nb * 16 + (lane & 15);
            int obase = wm * 64 + mb * 16 + (lane >> 4) * 4;
            us4v hv;
#pragma unroll
            for (int r = 0; r < 4; ++r)
                hv[r] = f2bf_rne(lrelu(acc[mb][nb][r] + b4[obase + r]));
            *(us4v*)&x2hi[((size_t)n * COLS + col) * 128 + obase] = hv;
        }
    }
}

// ---- k5 v3: M-split (M=64/block, grid 6400). Single-buffer wide-B (22.4KB),
//      depth-2 rolling A prefetch, T14 issue-early/write-late B staging, XCD swizzle. ----
__global__ __launch_bounds__(256) void k5_mfma(const unsigned short* __restrict__ wAhi,
                                               const unsigned short* __restrict__ x2hiT,
                                               const float* __restrict__ bcomb,
                                               float* __restrict__ out)
{
    __shared__ unsigned short Bh[280][40];   // 22.4 KB

    int bid = blockIdx.x;
    int swz = (bid & 7) * 800 + (bid >> 3);  // 6400 = 8*800, bijective; 16 n's per XCD
    int n = swz / 50;
    int rem = swz - n * 50;
    int ct = rem >> 1, om = rem & 1;         // om: which M-64-half; om-pairs adjacent -> same B in L2
    int c0 = ct * 128;
    int tid = threadIdx.x;
    int lane = tid & 63, wid = tid >> 6;
    int wm = wid & 1, wn = wid >> 1;         // wm: 32-row half of 64; wn: 64-col half of 128

    const unsigned short* x2h_n = x2hiT + (size_t)n * 409600;

    f32x4 acc[2][4];
#pragma unroll
    for (int a = 0; a < 2; ++a)
#pragma unroll
        for (int b = 0; b < 4; ++b) acc[a][b] = (f32x4)0.f;

    int rbase = lane & 15;
    int koff = (lane >> 4) * 8;
    int base = c0 - 75;
    int aoff[2];
#pragma unroll
    for (int mb = 0; mb < 2; ++mb)
        aoff[mb] = (om * 64 + wm * 32 + mb * 16 + rbase) * 1024 + koff;

    ushort8 bn[5];
    auto LOADB = [&](int icc) {
#pragma unroll
        for (int j = 0; j < 5; ++j) {
            int L = tid + j * 256;
            ushort8 v = (ushort8)0;
            if (L < 1112) {
                int w = L >> 2, g = (L & 3) * 8;
                int cs = base + w;
                if (cs >= 0 && cs < 3200)
                    v = *(const ushort8*)&x2h_n[(size_t)cs * 128 + icc * 32 + g];
            }
            bn[j] = v;
        }
    };
    auto WRITEB = [&]() {
#pragma unroll
        for (int j = 0; j < 5; ++j) {
            int L = tid + j * 256;
            if (L < 1112) {
                int w = L >> 2, g = (L & 3) * 8;
                *(ushort8*)&Bh[w][g] = bn[j];
            }
        }
    };

    LOADB(0);
    WRITEB();
    __syncthreads();

    for (int ic = 0; ic < 4; ++ic) {
        int i0 = ic * 32;
        // depth-2 rolling A prefetch
        short8 afc[2], afn[2];
#pragma unroll
        for (int mb = 0; mb < 2; ++mb) {
            afc[mb] = *(const short8*)&wAhi[aoff[mb] + i0];
            afn[mb] = *(const short8*)&wAhi[aoff[mb] + 128 + i0];
        }
        if (ic < 3) LOADB(ic + 1);      // issue next-ic B loads; written after barrier
#pragma unroll
        for (int tap = 0; tap < 8; ++tap) {
            short8 af[2] = {afc[0], afc[1]};
            afc[0] = afn[0]; afc[1] = afn[1];
            if (tap < 6) {
#pragma unroll
                for (int mb = 0; mb < 2; ++mb)
                    afn[mb] = *(const short8*)&wAhi[aoff[mb] + (tap + 2) * 128 + i0];
            }
            int wofs = (tap < 7) ? 25 * tap : 75;
            short8 bf[4];
#pragma unroll
            for (int nb = 0; nb < 4; ++nb)
                bf[nb] = *(const short8*)&Bh[wn * 64 + nb * 16 + rbase + wofs][koff];
#pragma unroll
            for (int mb = 0; mb < 2; ++mb)
#pragma unroll
                for (int nb = 0; nb < 4; ++nb)
                    acc[mb][nb] = __builtin_amdgcn_mfma_f32_16x16x32_bf16(af[mb], bf[nb], acc[mb][nb], 0, 0, 0);
        }
        __syncthreads();                 // all waves done reading Bh
        if (ic < 3) {
            WRITEB();                    // vmcnt waits for bn here, hidden under taps
            __syncthreads();
        }
    }
#pragma unroll
    for (int mb = 0; mb < 2; ++mb) {
#pragma unroll
        for (int nb = 0; nb < 4; ++nb) {
            int col = c0 + wn * 64 + nb * 16 + (lane & 15);
#pragma unroll
            for (int r = 0; r < 4; ++r) {
                int o = om * 64 + wm * 32 + mb * 16 + (lane >> 4) * 4 + r;
                float y = acc[mb][nb][r] + bcomb[o];
                out[((size_t)n * 128 + o) * 3200 + col] = lrelu(y);
            }
        }
    }
}

extern "C" void kernel_launch(void* const* d_in, const int* in_sizes, int n_in,
                              void* d_out, int out_size, void* d_ws, size_t ws_size,
                              hipStream_t stream)
{
    const float* x       = (const float*)d_in[0];
    const float* w_qkv   = (const float*)d_in[1];
    const float* b_qkv   = (const float*)d_in[2];
    const float* values  = (const float*)d_in[3];
    const float* att_bias= (const float*)d_in[4];
    const float* w_out   = (const float*)d_in[5];
    const float* b_out   = (const float*)d_in[6];
    const float* g_out   = (const float*)d_in[7];
    const float* be_out  = (const float*)d_in[8];
    const float* m_out   = (const float*)d_in[9];
    const float* v_out   = (const float*)d_in[10];
    const float* w_ff    = (const float*)d_in[11];
    const float* b_ff    = (const float*)d_in[12];
    const float* g_ff    = (const float*)d_in[13];
    const float* be_ff   = (const float*)d_in[14];
    const float* m_ff    = (const float*)d_in[15];
    const float* v_ff    = (const float*)d_in[16];
    const float* w_t     = (const float*)d_in[17];
    const float* b_t     = (const float*)d_in[18];
    const float* g_t     = (const float*)d_in[19];
    const float* be_t    = (const float*)d_in[20];
    const float* m_t     = (const float*)d_in[21];
    const float* v_t     = (const float*)d_in[22];
    const float* w_ress  = (const float*)d_in[23];
    const float* b_ress  = (const float*)d_in[24];
    const float* g_ress  = (const float*)d_in[25];
    const float* be_ress = (const float*)d_in[26];
    const float* m_ress  = (const float*)d_in[27];
    const float* v_ress  = (const float*)d_in[28];
    const float* w_rest  = (const float*)d_in[29];
    const float* b_rest  = (const float*)d_in[30];
    const float* g_rest  = (const float*)d_in[31];
    const float* be_rest = (const float*)d_in[32];
    const float* m_rest  = (const float*)d_in[33];
    const float* v_rest  = (const float*)d_in[34];

    float* ws = (float*)d_ws;
    float* out = (float*)d_out;

    unsigned short* xthi = (unsigned short*)(ws + OFF_XTHI);
    unsigned short* qk   = (unsigned short*)(ws + OFF_BIG);
    float*          part = ws + OFF_PART;
    unsigned short* tmhi = (unsigned short*)(ws + OFF_BIG);
    unsigned short* x2hi = (unsigned short*)(ws + OFF_BIG);
    unsigned short* x1hi = (unsigned short*)out;

    k0_prep<<<128, 256, 0, stream>>>(w_qkv,
        w_out, b_out, g_out, be_out, m_out, v_out,
        w_ff, b_ff, g_ff, be_ff, m_ff, v_ff,
        w_t, b_t, g_t, be_t, m_t, v_t,
        w_ress, b_ress, g_ress, be_ress, m_ress, v_ress,
        w_rest, b_rest, g_rest, be_rest, m_rest, v_rest,
        ws);
    k_xt<<<N_ * T_, 256, 0, stream>>>(x, xthi);
    k1_mfma<<<N_ * 25, 256, 0, stream>>>(
        (const unsigned short*)(ws + OFF_WQHI), xthi, b_qkv, qk);
    k2_att<<<N_ * H_ * 4, 256, 0, stream>>>(qk, part);
    k2b_smax<<<N_ * H_, 64, 0, stream>>>(part, values, att_bias, ws + OFF_ATT);
    k_tm<<<N_ * T_, 192, 0, stream>>>(x, ws + OFF_ATT, tmhi);
    k3_mfma<<<N_ * 25, 256, 0, stream>>>(
        (const unsigned short*)(ws + OFF_WA3HI), tmhi, xthi, ws + OFF_B3, x1hi);
    k4_mfma<<<N_ * 25, 256, 0, stream>>>(
        (const unsigned short*)(ws + OFF_WA4HI), x1hi, xthi, ws + OFF_B4, x2hi);
    k5_mfma<<<N_ * 50, 256, 0, stream>>>(
        (const unsigned short*)(ws + OFF_WA5HI), x2hi, ws + OFF_B5, out);
}

// Round 12
// 745.273 us; speedup vs baseline: 1.1152x; 1.0251x over previous
//
#include <hip/hip_runtime.h>

#define N_  128
#define C_  64
#define T_  128
#define V_  25
#define CO_ 128
#define H_  3
#define D_  16

constexpr int COLS = 3200;
constexpr float EPSF = 1e-5f;

typedef __attribute__((ext_vector_type(8))) short short8;
typedef __attribute__((ext_vector_type(8))) unsigned short ushort8;
typedef __attribute__((ext_vector_type(4))) unsigned short us4v;
typedef __attribute__((ext_vector_type(4))) float f32x4;

// ---- workspace layout (float units) ----
constexpr size_t OFF_ATT  = 0;                          // 240,000
constexpr size_t OFF_XTHI = 240000;                     // 13,107,200 fl (26.2M ushorts)
constexpr size_t OFF_BIG  = OFF_XTHI + 13107200;        // time-shared:
//   phase A: qk bf16 [n][96][3200] (19.7M fl) ; part at +20M fl
//   phase B: TmT bf16 [n][3200][192] (39.3M fl)
//   phase C: x2T bf16 [n][3200][128] (26.2M fl)
constexpr size_t BIGF     = 78643200;
constexpr size_t OFF_PART = OFF_BIG + 20000000;         // 960,000 floats (4*384*625)
constexpr size_t OFF_W    = OFF_BIG + BIGF;
constexpr size_t OFF_WQHI  = OFF_W;                     // 96*64 us = 3072 fl
constexpr size_t OFF_WA3HI = OFF_WQHI + 3072;           // 128*256 us = 16384 fl
constexpr size_t OFF_WA4HI = OFF_WA3HI + 16384;         // 128*192 us = 12288 fl
constexpr size_t OFF_WA5HI = OFF_WA4HI + 12288;         // 128*1024 us = 65536 fl
constexpr size_t OFF_B3    = OFF_WA5HI + 65536;
constexpr size_t OFF_B4    = OFF_B3 + 128;
constexpr size_t OFF_B5    = OFF_B4 + 128;

__device__ __forceinline__ float lrelu(float y) { return y >= 0.f ? y : 0.1f * y; }

__device__ __forceinline__ unsigned short f2bf_rne(float f) {
    unsigned int u = __builtin_bit_cast(unsigned int, f);
    u += 0x7FFFu + ((u >> 16) & 1u);
    return (unsigned short)(u >> 16);
}
__device__ __forceinline__ float bf2f(unsigned short b) {
    unsigned int u = ((unsigned int)b) << 16;
    return __builtin_bit_cast(float, u);
}

__device__ __forceinline__ void gload_lds16(const unsigned short* g, unsigned short* l) {
    __builtin_amdgcn_global_load_lds(
        (const __attribute__((address_space(1))) unsigned int*)g,
        (__attribute__((address_space(3))) unsigned int*)l,
        16, 0, 0);
}

// ---- K0: BN-fold + bf16 A-operands (single plane) ----
__global__ void k0_prep(const float* __restrict__ w_qkv,
                        const float* __restrict__ w_out, const float* __restrict__ b_out,
                        const float* __restrict__ g_out, const float* __restrict__ be_out,
                        const float* __restrict__ m_out, const float* __restrict__ v_out,
                        const float* __restrict__ w_ff,  const float* __restrict__ b_ff,
                        const float* __restrict__ g_ff,  const float* __restrict__ be_ff,
                        const float* __restrict__ m_ff,  const float* __restrict__ v_ff,
                        const float* __restrict__ w_t,   const float* __restrict__ b_t,
                        const float* __restrict__ g_t,   const float* __restrict__ be_t,
                        const float* __restrict__ m_t,   const float* __restrict__ v_t,
                        const float* __restrict__ w_ress,const float* __restrict__ b_ress,
                        const float* __restrict__ g_ress,const float* __restrict__ be_ress,
                        const float* __restrict__ m_ress,const float* __restrict__ v_ress,
                        const float* __restrict__ w_rest,const float* __restrict__ b_rest,
                        const float* __restrict__ g_rest,const float* __restrict__ be_rest,
                        const float* __restrict__ m_rest,const float* __restrict__ v_rest,
                        float* __restrict__ ws)
{
    int tid = blockIdx.x * blockDim.x + threadIdx.x;
    int np = gridDim.x * blockDim.x;

    unsigned short* wqh = (unsigned short*)(ws + OFF_WQHI);
    for (int idx = tid; idx < 96 * 64; idx += np)
        wqh[idx] = f2bf_rne(w_qkv[idx]);

    unsigned short* w3h = (unsigned short*)(ws + OFF_WA3HI);
    for (int idx = tid; idx < 128 * 256; idx += np) {
        int o = idx >> 8, k = idx & 255;
        float val;
        if (k < 192) {
            float sc = g_out[o] * rsqrtf(v_out[o] + EPSF);
            val = w_out[o * 192 + k] * sc;
        } else {
            float sc = g_ress[o] * rsqrtf(v_ress[o] + EPSF);
            val = w_ress[o * 64 + (k - 192)] * sc;
        }
        w3h[idx] = f2bf_rne(val);
    }

    unsigned short* w4h = (unsigned short*)(ws + OFF_WA4HI);
    for (int idx = tid; idx < 128 * 192; idx += np) {
        int o = idx / 192, k = idx % 192;
        float val;
        if (k < 128) {
            float sc = g_ff[o] * rsqrtf(v_ff[o] + EPSF);
            val = w_ff[o * 128 + k] * sc;
        } else {
            float sc = g_ress[o] * rsqrtf(v_ress[o] + EPSF);
            val = w_ress[o * 64 + (k - 128)] * sc;
        }
        w4h[idx] = f2bf_rne(val);
    }

    unsigned short* w5h = (unsigned short*)(ws + OFF_WA5HI);
    for (int idx = tid; idx < 128 * 1024; idx += np) {
        int o = idx >> 10, kk = idx & 1023;
        int tap = kk >> 7, i = kk & 127;
        float val;
        if (tap < 7) {
            float sc = g_t[o] * rsqrtf(v_t[o] + EPSF);
            val = w_t[((size_t)o * 128 + i) * 7 + tap] * sc;
        } else {
            float sc = g_rest[o] * rsqrtf(v_rest[o] + EPSF);
            val = w_rest[o * 128 + i] * sc;
        }
        w5h[idx] = f2bf_rne(val);
    }

    for (int o = tid; o < 128; o += np) {
        float sco = g_out[o] * rsqrtf(v_out[o] + EPSF);
        float scr = g_ress[o] * rsqrtf(v_ress[o] + EPSF);
        float scf = g_ff[o] * rsqrtf(v_ff[o] + EPSF);
        float sct = g_t[o] * rsqrtf(v_t[o] + EPSF);
        float sce = g_rest[o] * rsqrtf(v_rest[o] + EPSF);
        float bres = (b_ress[o] - m_ress[o]) * scr + be_ress[o];
        ws[OFF_B3 + o] = (b_out[o] - m_out[o]) * sco + be_out[o] + bres;
        ws[OFF_B4 + o] = (b_ff[o] - m_ff[o]) * scf + be_ff[o] + bres;
        ws[OFF_B5 + o] = (b_t[o] - m_t[o]) * sct + be_t[o]
                       + (b_rest[o] - m_rest[o]) * sce + be_rest[o];
    }
}

// ---- k_xt: x[n][c][t][v] -> xT[n][col][64] bf16 ----
__global__ __launch_bounds__(256) void k_xt(const float* __restrict__ x,
                                            unsigned short* __restrict__ xthi)
{
    __shared__ float Xs[64][26];
    int nt = blockIdx.x;
    int n = nt >> 7, t = nt & 127;
    const float* xb = x + ((size_t)n * C_ * T_ + t) * V_;
    for (int e = threadIdx.x; e < 1600; e += 256) {
        int c = e / 25, u = e % 25;
        Xs[c][u] = xb[(size_t)c * (T_ * V_) + u];
    }
    __syncthreads();
    unsigned short* dh = xthi + ((size_t)n * COLS + t * 25) * 64;
    for (int e = threadIdx.x; e < 1600; e += 256) {
        int v = e >> 6, c = e & 63;
        dh[(size_t)v * 64 + c] = f2bf_rne(Xs[c][v]);
    }
}

// ---- k1: qkv GEMM M=96,K=64 -> qk bf16 [n][96][3200] ----
__global__ __launch_bounds__(256, 2) void k1_mfma(const unsigned short* __restrict__ wqh,
                                                   const unsigned short* __restrict__ xthi,
                                                   const float* __restrict__ b_qkv,
                                                   unsigned short* __restrict__ qk)
{
    __shared__ unsigned short Ah[96][40], Bh[128][40];
    int blk = blockIdx.x;
    int n = blk / 25, ct = blk % 25;
    int c0 = ct * 128;
    int tid = threadIdx.x, lane = tid & 63, wid = tid >> 6;
    int wm = wid & 1, wn = wid >> 1;
    const unsigned short* xh = xthi + (size_t)n * COLS * 64;
    f32x4 acc[3][4];
#pragma unroll
    for (int a = 0; a < 3; ++a)
#pragma unroll
        for (int b = 0; b < 4; ++b) acc[a][b] = (f32x4)0.f;
    int rbase = lane & 15, koff = (lane >> 4) * 8;

    for (int ks = 0; ks < 2; ++ks) {
        __syncthreads();
        for (int L = tid; L < 384; L += 256) {
            int o = L >> 2, g = (L & 3) * 8;
            *(ushort8*)&Ah[o][g] = *(const ushort8*)&wqh[(size_t)o * 64 + ks * 32 + g];
        }
        for (int L = tid; L < 512; L += 256) {
            int col = L >> 2, g = (L & 3) * 8;
            size_t src = (size_t)(c0 + col) * 64 + ks * 32 + g;
            *(ushort8*)&Bh[col][g] = *(const ushort8*)&xh[src];
        }
        __syncthreads();
        short8 afh[3], bfh[4];
#pragma unroll
        for (int mb = 0; mb < 3; ++mb)
            afh[mb] = *(const short8*)&Ah[wm * 48 + mb * 16 + rbase][koff];
#pragma unroll
        for (int nb = 0; nb < 4; ++nb)
            bfh[nb] = *(const short8*)&Bh[wn * 64 + nb * 16 + rbase][koff];
#pragma unroll
        for (int mb = 0; mb < 3; ++mb)
#pragma unroll
            for (int nb = 0; nb < 4; ++nb)
                acc[mb][nb] = __builtin_amdgcn_mfma_f32_16x16x32_bf16(afh[mb], bfh[nb], acc[mb][nb], 0, 0, 0);
    }
#pragma unroll
    for (int mb = 0; mb < 3; ++mb) {
#pragma unroll
        for (int nb = 0; nb < 4; ++nb) {
            int col = c0 + wn * 64 + nb * 16 + (lane & 15);
#pragma unroll
            for (int r = 0; r < 4; ++r) {
                int o = wm * 48 + mb * 16 + (lane >> 4) * 4 + r;
                qk[((size_t)n * 96 + o) * COLS + col] = f2bf_rne(acc[mb][nb][r] + b_qkv[o]);
            }
        }
    }
}

// ---- k2: partial attention logits (T split 4-way) -> part[p][nh][u][v] ----
__global__ __launch_bounds__(256) void k2_att(const unsigned short* __restrict__ qk,
                                              float* __restrict__ part)
{
    int blk = blockIdx.x;
    int nh = blk >> 2, p = blk & 3;
    int n = nh / H_, h = nh % H_;
    __shared__ float Qs[D_][8][26];
    __shared__ float Ks[D_][8][26];
    float acc[3] = {0.f, 0.f, 0.f};
    const unsigned short* qbase = qk + (size_t)(n * 96 + h * 16) * COLS;
    const unsigned short* kbase = qk + (size_t)(n * 96 + 48 + h * 16) * COLS;
    for (int tc = p * 32; tc < p * 32 + 32; tc += 8) {
        __syncthreads();
        for (int e = threadIdx.x; e < 16 * 8 * 25; e += 256) {
            int d = e / 200, r = e % 200;
            int tt = r / 25, u = r % 25;
            Qs[d][tt][u] = bf2f(qbase[(size_t)d * COLS + (tc + tt) * 25 + u]);
            Ks[d][tt][u] = bf2f(kbase[(size_t)d * COLS + (tc + tt) * 25 + u]);
        }
        __syncthreads();
#pragma unroll
        for (int q = 0; q < 3; ++q) {
            int e = threadIdx.x + q * 256;
            if (e < 625) {
                int u = e / 25, v = e % 25;
                float a = acc[q];
                for (int tt = 0; tt < 8; ++tt) {
#pragma unroll
                    for (int d = 0; d < 16; ++d)
                        a += Qs[d][tt][u] * Ks[d][tt][v];
                }
                acc[q] = a;
            }
        }
    }
    float* pb = part + ((size_t)p * 384 + nh) * 625;
#pragma unroll
    for (int q = 0; q < 3; ++q) {
        int e = threadIdx.x + q * 256;
        if (e < 625) pb[e] = acc[q];
    }
}

// ---- k2b: combine partials + softmax -> att[n,h,u,v] ----
__global__ __launch_bounds__(64) void k2b_smax(const float* __restrict__ part,
                                               const float* __restrict__ values,
                                               const float* __restrict__ att_bias,
                                               float* __restrict__ att)
{
    int nh = blockIdx.x;
    int h = nh % H_;
    if (threadIdx.x < 25) {
        int u = threadIdx.x;
        float scale = values[h] / 2048.0f;
        float bias = att_bias[h];
        float L[25];
        float m = -1e30f;
        for (int v = 0; v < 25; ++v) {
            size_t idx = (size_t)nh * 625 + u * 25 + v;
            float s = part[idx] + part[384 * 625 + idx] + part[2 * 384 * 625 + idx]
                    + part[3 * 384 * 625 + idx];
            L[v] = s * scale + bias;
            m = fmaxf(m, L[v]);
        }
        float ex[25];
        float s = 0.f;
        for (int v = 0; v < 25; ++v) { ex[v] = expf(L[v] - m); s += ex[v]; }
        float inv = 1.0f / s;
        float* ab = att + (size_t)nh * 625 + u * 25;
        for (int v = 0; v < 25; ++v) ab[v] = ex[v] * inv;
    }
}

// ---- k_tm: Tm[hc][t,v] = sum_u x[c][t,u]*att[h][u][v] -> TmT[n][col][192] bf16 ----
__global__ __launch_bounds__(192) void k_tm(const float* __restrict__ x,
                                            const float* __restrict__ att,
                                            unsigned short* __restrict__ tmhi)
{
    __shared__ float Xs[64][26];
    __shared__ float As[3][25][26];
    int nt = blockIdx.x;
    int n = nt >> 7, t = nt & 127;
    const float* xb = x + ((size_t)n * C_ * T_ + t) * V_;
    for (int e = threadIdx.x; e < 1600; e += 192) {
        int c = e / 25, u = e % 25;
        Xs[c][u] = xb[(size_t)c * (T_ * V_) + u];
    }
    const float* ab = att + (size_t)n * 3 * 625;
    for (int e = threadIdx.x; e < 1875; e += 192) {
        int h = e / 625, r = e % 625;
        As[h][r / 25][r % 25] = ab[e];
    }
    __syncthreads();
    int hc = threadIdx.x;
    int h = hc >> 6, c = hc & 63;
    float xr[25];
#pragma unroll
    for (int u = 0; u < 25; ++u) xr[u] = Xs[c][u];
    unsigned short* dh = tmhi + ((size_t)n * COLS + t * 25) * 192 + hc;
#pragma unroll 5
    for (int v = 0; v < 25; ++v) {
        float a = 0.f;
#pragma unroll
        for (int u = 0; u < 25; ++u) a += xr[u] * As[h][u][v];
        dh[(size_t)v * 192] = f2bf_rne(a);
    }
}

// ---- k3: x1 GEMM M=128,K=256 (192 Tm + 64 x) -> x1T bf16 (in d_out) ----
__global__ __launch_bounds__(256, 2) void k3_mfma(const unsigned short* __restrict__ w3h,
                                                   const unsigned short* __restrict__ tmhi,
                                                   const unsigned short* __restrict__ xthi,
                                                   const float* __restrict__ b3,
                                                   unsigned short* __restrict__ x1hi)
{
    __shared__ unsigned short Ah[128][40], Bh[128][40];
    int blk = blockIdx.x;
    int n = blk / 25, ct = blk % 25;
    int c0 = ct * 128;
    int tid = threadIdx.x, lane = tid & 63, wid = tid >> 6;
    int wm = wid & 1, wn = wid >> 1;
    const unsigned short* th = tmhi + (size_t)n * COLS * 192;
    const unsigned short* xh = xthi + (size_t)n * COLS * 64;
    f32x4 acc[4][4];
#pragma unroll
    for (int a = 0; a < 4; ++a)
#pragma unroll
        for (int b = 0; b < 4; ++b) acc[a][b] = (f32x4)0.f;
    int rbase = lane & 15, koff = (lane >> 4) * 8;

    for (int ks = 0; ks < 8; ++ks) {
        __syncthreads();
        for (int L = tid; L < 512; L += 256) {
            int o = L >> 2, g = (L & 3) * 8;
            *(ushort8*)&Ah[o][g] = *(const ushort8*)&w3h[(size_t)o * 256 + ks * 32 + g];
        }
        for (int L = tid; L < 512; L += 256) {
            int col = L >> 2, g = (L & 3) * 8;
            ushort8 vh;
            if (ks < 6) {
                vh = *(const ushort8*)&th[(size_t)(c0 + col) * 192 + ks * 32 + g];
            } else {
                vh = *(const ushort8*)&xh[(size_t)(c0 + col) * 64 + (ks - 6) * 32 + g];
            }
            *(ushort8*)&Bh[col][g] = vh;
        }
        __syncthreads();
        short8 afh[4], bfh[4];
#pragma unroll
        for (int mb = 0; mb < 4; ++mb)
            afh[mb] = *(const short8*)&Ah[wm * 64 + mb * 16 + rbase][koff];
#pragma unroll
        for (int nb = 0; nb < 4; ++nb)
            bfh[nb] = *(const short8*)&Bh[wn * 64 + nb * 16 + rbase][koff];
#pragma unroll
        for (int mb = 0; mb < 4; ++mb)
#pragma unroll
            for (int nb = 0; nb < 4; ++nb)
                acc[mb][nb] = __builtin_amdgcn_mfma_f32_16x16x32_bf16(afh[mb], bfh[nb], acc[mb][nb], 0, 0, 0);
    }
#pragma unroll
    for (int mb = 0; mb < 4; ++mb) {
#pragma unroll
        for (int nb = 0; nb < 4; ++nb) {
            int col = c0 + wn * 64 + nb * 16 + (lane & 15);
            int obase = wm * 64 + mb * 16 + (lane >> 4) * 4;
            us4v hv;
#pragma unroll
            for (int r = 0; r < 4; ++r)
                hv[r] = f2bf_rne(lrelu(acc[mb][nb][r] + b3[obase + r]));
            *(us4v*)&x1hi[((size_t)n * COLS + col) * 128 + obase] = hv;
        }
    }
}

// ---- k4: x2 GEMM M=128,K=192 (128 x1 + 64 x) -> x2T bf16 ----
__global__ __launch_bounds__(256, 2) void k4_mfma(const unsigned short* __restrict__ w4h,
                                                   const unsigned short* __restrict__ x1hi,
                                                   const unsigned short* __restrict__ xthi,
                                                   const float* __restrict__ b4,
                                                   unsigned short* __restrict__ x2hi)
{
    __shared__ unsigned short Ah[128][40], Bh[128][40];
    int blk = blockIdx.x;
    int n = blk / 25, ct = blk % 25;
    int c0 = ct * 128;
    int tid = threadIdx.x, lane = tid & 63, wid = tid >> 6;
    int wm = wid & 1, wn = wid >> 1;
    const unsigned short* ph = x1hi + (size_t)n * COLS * 128;
    const unsigned short* xh = xthi + (size_t)n * COLS * 64;
    f32x4 acc[4][4];
#pragma unroll
    for (int a = 0; a < 4; ++a)
#pragma unroll
        for (int b = 0; b < 4; ++b) acc[a][b] = (f32x4)0.f;
    int rbase = lane & 15, koff = (lane >> 4) * 8;

    for (int ks = 0; ks < 6; ++ks) {
        __syncthreads();
        for (int L = tid; L < 512; L += 256) {
            int o = L >> 2, g = (L & 3) * 8;
            *(ushort8*)&Ah[o][g] = *(const ushort8*)&w4h[(size_t)o * 192 + ks * 32 + g];
        }
        for (int L = tid; L < 512; L += 256) {
            int col = L >> 2, g = (L & 3) * 8;
            ushort8 vh;
            if (ks < 4) {
                vh = *(const ushort8*)&ph[(size_t)(c0 + col) * 128 + ks * 32 + g];
            } else {
                vh = *(const ushort8*)&xh[(size_t)(c0 + col) * 64 + (ks - 4) * 32 + g];
            }
            *(ushort8*)&Bh[col][g] = vh;
        }
        __syncthreads();
        short8 afh[4], bfh[4];
#pragma unroll
        for (int mb = 0; mb < 4; ++mb)
            afh[mb] = *(const short8*)&Ah[wm * 64 + mb * 16 + rbase][koff];
#pragma unroll
        for (int nb = 0; nb < 4; ++nb)
            bfh[nb] = *(const short8*)&Bh[wn * 64 + nb * 16 + rbase][koff];
#pragma unroll
        for (int mb = 0; mb < 4; ++mb)
#pragma unroll
            for (int nb = 0; nb < 4; ++nb)
                acc[mb][nb] = __builtin_amdgcn_mfma_f32_16x16x32_bf16(afh[mb], bfh[nb], acc[mb][nb], 0, 0, 0);
    }
#pragma unroll
    for (int mb = 0; mb < 4; ++mb) {
#pragma unroll
        for (int nb = 0; nb < 4; ++nb) {
            int col = c0 + wn * 64 + nb * 16 + (lane & 15);
            int obase = wm * 64 + mb * 16 + (lane >> 4) * 4;
            us4v hv;
#pragma unroll
            for (int r = 0; r < 4; ++r)
                hv[r] = f2bf_rne(lrelu(acc[mb][nb][r] + b4[obase + r]));
            *(us4v*)&x2hi[((size_t)n * COLS + col) * 128 + obase] = hv;
        }
    }
}

// ---- k5 v4: M=64 blocks; B via global_load_lds (async, double-buffered, XOR-swizzled
//      packed LDS); full 8-tap A register prefetch issued BEFORE B batch; XCD swizzle. ----
__global__ __launch_bounds__(256) void k5_mfma(const unsigned short* __restrict__ wAhi,
                                               const unsigned short* __restrict__ x2hiT,
                                               const float* __restrict__ bcomb,
                                               float* __restrict__ out)
{
    // packed: chunk L (0..1111) at byte L*16; row w = L>>2 (64B/row), kchunk' = L&3.
    // swizzle: stored kchunk' holds global kchunk = kchunk' ^ ((w>>1)&3).
    __shared__ unsigned short Bh[2][8896];   // 2 x 17792 B

    int bid = blockIdx.x;
    int swz = (bid & 7) * 800 + (bid >> 3);  // 6400 = 8*800, bijective
    int n = swz / 50;
    int rem = swz - n * 50;
    int ct = rem >> 1, om = rem & 1;
    int c0 = ct * 128;
    int tid = threadIdx.x;
    int lane = tid & 63, wid = tid >> 6;
    int wm = wid & 1, wn = wid >> 1;         // wave tile: 32 rows x 64 cols

    const unsigned short* xb = x2hiT + (size_t)n * 409600;
    int base = c0 - 75;

    // pre-zero halo chunks (edge blocks only; those lanes never load)
    if (ct == 0 || ct == 24) {
        for (int L = tid; L < 1112; L += 256) {
            int w = L >> 2;
            int cs = base + w;
            if (cs < 0 || cs >= 3200) {
                *(ushort8*)((char*)&Bh[0][0] + L * 16) = (ushort8)0;
                *(ushort8*)((char*)&Bh[1][0] + L * 16) = (ushort8)0;
            }
        }
    }

    auto LOADB = [&](int buf, int icc) {
#pragma unroll
        for (int j = 0; j < 5; ++j) {
            int L = tid + j * 256;
            if (L < 1112) {
                int w = L >> 2, kcp = L & 3;
                int cs = base + w;
                if (cs >= 0 && cs < 3200) {
                    int kc = kcp ^ ((w >> 1) & 3);
                    gload_lds16(&xb[(size_t)cs * 128 + icc * 32 + kc * 8],
                                (unsigned short*)((char*)&Bh[buf][0] + j * 4096 + wid * 1024));
                }
            }
        }
    };

    f32x4 acc[2][4];
#pragma unroll
    for (int a = 0; a < 2; ++a)
#pragma unroll
        for (int b = 0; b < 4; ++b) acc[a][b] = (f32x4)0.f;

    int rbase = lane & 15;
    int kc = lane >> 4;                      // 0..3 (16B k-chunk index)
    int koff = kc * 8;
    int aoff[2];
#pragma unroll
    for (int mb = 0; mb < 2; ++mb)
        aoff[mb] = (om * 64 + wm * 32 + mb * 16 + rbase) * 1024 + koff;

    LOADB(0, 0);
    __syncthreads();

    for (int ic = 0; ic < 4; ++ic) {
        int i0 = ic * 32;
        int cur = ic & 1;
        // full 8-tap A prefetch FIRST (so A-waits never drain the B batch issued after)
        short8 afT[8][2];
#pragma unroll
        for (int t = 0; t < 8; ++t)
#pragma unroll
            for (int mb = 0; mb < 2; ++mb)
                afT[t][mb] = *(const short8*)&wAhi[aoff[mb] + t * 128 + i0];
        if (ic < 3) LOADB(cur ^ 1, ic + 1);  // async into other buffer; drains at end barrier
#pragma unroll
        for (int tap = 0; tap < 8; ++tap) {
            int wofs = (tap < 7) ? 25 * tap : 75;
            short8 bf[4];
#pragma unroll
            for (int nb = 0; nb < 4; ++nb) {
                int row = wn * 64 + nb * 16 + rbase + wofs;
                int kcs = kc ^ ((row >> 1) & 3);
                bf[nb] = *(const short8*)((const char*)&Bh[cur][0] + row * 64 + kcs * 16);
            }
#pragma unroll
            for (int mb = 0; mb < 2; ++mb)
#pragma unroll
                for (int nb = 0; nb < 4; ++nb)
                    acc[mb][nb] = __builtin_amdgcn_mfma_f32_16x16x32_bf16(afT[tap][mb], bf[nb], acc[mb][nb], 0, 0, 0);
        }
        __syncthreads();
    }
#pragma unroll
    for (int mb = 0; mb < 2; ++mb) {
#pragma unroll
        for (int nb = 0; nb < 4; ++nb) {
            int col = c0 + wn * 64 + nb * 16 + (lane & 15);
#pragma unroll
            for (int r = 0; r < 4; ++r) {
                int o = om * 64 + wm * 32 + mb * 16 + (lane >> 4) * 4 + r;
                float y = acc[mb][nb][r] + bcomb[o];
                out[((size_t)n * 128 + o) * 3200 + col] = lrelu(y);
            }
        }
    }
}

extern "C" void kernel_launch(void* const* d_in, const int* in_sizes, int n_in,
                              void* d_out, int out_size, void* d_ws, size_t ws_size,
                              hipStream_t stream)
{
    const float* x       = (const float*)d_in[0];
    const float* w_qkv   = (const float*)d_in[1];
    const float* b_qkv   = (const float*)d_in[2];
    const float* values  = (const float*)d_in[3];
    const float* att_bias= (const float*)d_in[4];
    const float* w_out   = (const float*)d_in[5];
    const float* b_out   = (const float*)d_in[6];
    const float* g_out   = (const float*)d_in[7];
    const float* be_out  = (const float*)d_in[8];
    const float* m_out   = (const float*)d_in[9];
    const float* v_out   = (const float*)d_in[10];
    const float* w_ff    = (const float*)d_in[11];
    const float* b_ff    = (const float*)d_in[12];
    const float* g_ff    = (const float*)d_in[13];
    const float* be_ff   = (const float*)d_in[14];
    const float* m_ff    = (const float*)d_in[15];
    const float* v_ff    = (const float*)d_in[16];
    const float* w_t     = (const float*)d_in[17];
    const float* b_t     = (const float*)d_in[18];
    const float* g_t     = (const float*)d_in[19];
    const float* be_t    = (const float*)d_in[20];
    const float* m_t     = (const float*)d_in[21];
    const float* v_t     = (const float*)d_in[22];
    const float* w_ress  = (const float*)d_in[23];
    const float* b_ress  = (const float*)d_in[24];
    const float* g_ress  = (const float*)d_in[25];
    const float* be_ress = (const float*)d_in[26];
    const float* m_ress  = (const float*)d_in[27];
    const float* v_ress  = (const float*)d_in[28];
    const float* w_rest  = (const float*)d_in[29];
    const float* b_rest  = (const float*)d_in[30];
    const float* g_rest  = (const float*)d_in[31];
    const float* be_rest = (const float*)d_in[32];
    const float* m_rest  = (const float*)d_in[33];
    const float* v_rest  = (const float*)d_in[34];

    float* ws = (float*)d_ws;
    float* out = (float*)d_out;

    unsigned short* xthi = (unsigned short*)(ws + OFF_XTHI);
    unsigned short* qk   = (unsigned short*)(ws + OFF_BIG);
    float*          part = ws + OFF_PART;
    unsigned short* tmhi = (unsigned short*)(ws + OFF_BIG);
    unsigned short* x2hi = (unsigned short*)(ws + OFF_BIG);
    unsigned short* x1hi = (unsigned short*)out;

    k0_prep<<<128, 256, 0, stream>>>(w_qkv,
        w_out, b_out, g_out, be_out, m_out, v_out,
        w_ff, b_ff, g_ff, be_ff, m_ff, v_ff,
        w_t, b_t, g_t, be_t, m_t, v_t,
        w_ress, b_ress, g_ress, be_ress, m_ress, v_ress,
        w_rest, b_rest, g_rest, be_rest, m_rest, v_rest,
        ws);
    k_xt<<<N_ * T_, 256, 0, stream>>>(x, xthi);
    k1_mfma<<<N_ * 25, 256, 0, stream>>>(
        (const unsigned short*)(ws + OFF_WQHI), xthi, b_qkv, qk);
    k2_att<<<N_ * H_ * 4, 256, 0, stream>>>(qk, part);
    k2b_smax<<<N_ * H_, 64, 0, stream>>>(part, values, att_bias, ws + OFF_ATT);
    k_tm<<<N_ * T_, 192, 0, stream>>>(x, ws + OFF_ATT, tmhi);
    k3_mfma<<<N_ * 25, 256, 0, stream>>>(
        (const unsigned short*)(ws + OFF_WA3HI), tmhi, xthi, ws + OFF_B3, x1hi);
    k4_mfma<<<N_ * 25, 256, 0, stream>>>(
        (const unsigned short*)(ws + OFF_WA4HI), x1hi, xthi, ws + OFF_B4, x2hi);
    k5_mfma<<<N_ * 50, 256, 0, stream>>>(
        (const unsigned short*)(ws + OFF_WA5HI), x2hi, ws + OFF_B5, out);
}